// Round 1
// baseline (618.186 us; speedup 1.0000x reference)
//
#include <hip/hip_runtime.h>
#include <math.h>

// ---------------------------------------------------------------------------
// SABlock_CrossMamba: 4x mamba variants (k=1,2,4,8) + LN residuals + freq-FFN
// fp32 throughout. DFT via exact mod-512 cos/sin tables.
// ---------------------------------------------------------------------------

constexpr int Bt = 4, Lt = 512, Dm = 128, Di = 256, Sn = 64, Rr = 8, Hh = 256;
constexpr int NT = Bt * Lt;            // 2048 tokens
constexpr float EPSF = 1e-5f;
constexpr float LOG2E = 1.4426950408889634f;
constexpr float ISQ512 = 0.04419417382415922f;  // 1/sqrt(512)

// ws layout (float offsets)
constexpr long O_CTAB = 0;                       // 512*512
constexpr long O_STAB = O_CTAB + 512L * 512;     // 512*512
constexpr long O_A2   = O_STAB + 512L * 512;     // 256*64
constexpr long O_FC1T = O_A2 + 256L * 64;        // 128*256
constexpr long O_FC2T = O_FC1T + 128L * 256;     // 256*128
constexpr long O_RD   = O_FC2T + 256L * 128;     // 256
constexpr long O_IDG  = O_RD + 256;              // 256
constexpr long O_XN   = O_IDG + 256;             // NT*128
constexpr long O_XZ   = O_XN + (long)NT * Dm;    // NT*512
constexpr long O_XH   = O_XZ + (long)NT * 512;   // 4*NT*256
constexpr long O_DBL  = O_XH + 4L * NT * Di;     // 4*NT*136
constexpr long O_DT   = O_DBL + 4L * NT * 136;   // 4*NT*256
constexpr long O_YS   = O_DT + 4L * NT * Di;     // 4*NT*256
constexpr long O_YACC = O_YS + 4L * NT * Di;     // NT*256
constexpr long O_XO1  = O_YACC + (long)NT * Di;  // NT*128
constexpr long O_XO   = O_XO1 + (long)NT * Dm;   // NT*128
constexpr long O_LN2  = O_XO + (long)NT * Dm;    // NT*128
constexpr long O_H1   = O_LN2 + (long)NT * Dm;   // NT*256
constexpr long O_H1N  = O_H1 + (long)NT * Hh;    // NT*256
constexpr long O_XR   = O_H1N + (long)NT * Hh;   // NT*256
constexpr long O_XI   = O_XR + (long)NT * Hh;    // NT*256
constexpr long O_H2   = O_XI + (long)NT * Hh;    // NT*256
constexpr long O_F2   = O_H2 + (long)NT * Hh;    // NT*128
constexpr long O_ST1  = O_F2 + (long)NT * Dm;    // 512 (scale1|shift1)
constexpr long O_ST2  = O_ST1 + 512;             // 256 (scale2|shift2)

// ---------------------------------------------------------------------------
__global__ void k_tables(const float* __restrict__ A_log,
                         const float* __restrict__ fc1_w,
                         const float* __restrict__ fc2_w,
                         const float* __restrict__ r_mat,
                         const float* __restrict__ i_mat,
                         float* __restrict__ ws) {
  int i = blockIdx.x * 256 + threadIdx.x;   // grid covers 262144
  {
    int k = i >> 9, n = i & 511;
    int m = (k * n) & 511;
    float ang = (float)m * (6.283185307179586f / 512.0f);
    float s, c;
    sincosf(ang, &s, &c);
    ws[O_CTAB + i] = c * ISQ512;
    ws[O_STAB + i] = -s * ISQ512;
  }
  if (i < 256 * 64) ws[O_A2 + i] = -expf(A_log[i]) * LOG2E;
  if (i < 128 * 256) {  // fc1t[c][h] = fc1_w[h][c]
    int c = i >> 8, h = i & 255;
    ws[O_FC1T + i] = fc1_w[h * 128 + c];
  }
  if (i < 256 * 128) {  // fc2t[h][c] = fc2_w[c][h]
    int h = i >> 7, c = i & 127;
    ws[O_FC2T + i] = fc2_w[c * 256 + h];
  }
  if (i < 256) {
    ws[O_RD + i] = r_mat[i * 256 + i];
    ws[O_IDG + i] = i_mat[i * 256 + i];
  }
}

// ---------------------------------------------------------------------------
// LayerNorm over D=128, one wave per token
__global__ void k_ln1(const float* __restrict__ x, const float* __restrict__ w,
                      const float* __restrict__ b, float* __restrict__ out) {
  int lane = threadIdx.x & 63;
  int t = (blockIdx.x * 256 + threadIdx.x) >> 6;
  float v0 = x[t * 128 + lane], v1 = x[t * 128 + 64 + lane];
  float s = v0 + v1, sq = v0 * v0 + v1 * v1;
#pragma unroll
  for (int off = 32; off; off >>= 1) { s += __shfl_xor(s, off); sq += __shfl_xor(sq, off); }
  float mu = s * (1.f / 128.f);
  float rstd = rsqrtf(sq * (1.f / 128.f) - mu * mu + EPSF);
  out[t * 128 + lane]      = (v0 - mu) * rstd * w[lane] + b[lane];
  out[t * 128 + 64 + lane] = (v1 - mu) * rstd * w[64 + lane] + b[64 + lane];
}

// xo = x + LN(x_o)*w1+b1 ; ln2 = LN(xo)*w2+b2
__global__ void k_lndbl(const float* __restrict__ x, const float* __restrict__ xo1,
                        const float* __restrict__ w1, const float* __restrict__ b1,
                        const float* __restrict__ w2, const float* __restrict__ b2,
                        float* __restrict__ xo, float* __restrict__ ln2) {
  int lane = threadIdx.x & 63;
  int t = (blockIdx.x * 256 + threadIdx.x) >> 6;
  float u0 = xo1[t * 128 + lane], u1 = xo1[t * 128 + 64 + lane];
  float s = u0 + u1, sq = u0 * u0 + u1 * u1;
#pragma unroll
  for (int off = 32; off; off >>= 1) { s += __shfl_xor(s, off); sq += __shfl_xor(sq, off); }
  float mu = s * (1.f / 128.f);
  float rstd = rsqrtf(sq * (1.f / 128.f) - mu * mu + EPSF);
  float a0 = x[t * 128 + lane]      + (u0 - mu) * rstd * w1[lane] + b1[lane];
  float a1 = x[t * 128 + 64 + lane] + (u1 - mu) * rstd * w1[64 + lane] + b1[64 + lane];
  xo[t * 128 + lane] = a0;
  xo[t * 128 + 64 + lane] = a1;
  s = a0 + a1; sq = a0 * a0 + a1 * a1;
#pragma unroll
  for (int off = 32; off; off >>= 1) { s += __shfl_xor(s, off); sq += __shfl_xor(sq, off); }
  mu = s * (1.f / 128.f);
  rstd = rsqrtf(sq * (1.f / 128.f) - mu * mu + EPSF);
  ln2[t * 128 + lane]      = (a0 - mu) * rstd * w2[lane] + b2[lane];
  ln2[t * 128 + 64 + lane] = (a1 - mu) * rstd * w2[64 + lane] + b2[64 + lane];
}

// ---------------------------------------------------------------------------
// Generic tiled fp32 GEMM: C = [C +] A@B. Row-major. M%64==0, K%16==0, N%4==0.
template <bool ACC>
__global__ __launch_bounds__(256) void k_gemm(const float* __restrict__ A,
                                              const float* __restrict__ B,
                                              float* __restrict__ C,
                                              int M, int N, int K,
                                              long sA, long sB, long sC) {
  A += (long)blockIdx.z * sA;
  B += (long)blockIdx.z * sB;
  C += (long)blockIdx.z * sC;
  __shared__ float As[16][68];
  __shared__ float Bs[16][68];
  int tid = threadIdx.x;
  int m0 = blockIdx.y * 64, n0 = blockIdx.x * 64;
  int arow = tid >> 2, ak4 = (tid & 3) * 4;
  int bkrow = tid >> 4, bn4 = (tid & 15) * 4;
  int tr = (tid >> 4) * 4, tc = (tid & 15) * 4;
  float acc[4][4] = {};
  for (int k0 = 0; k0 < K; k0 += 16) {
    float4 av = *(const float4*)&A[(long)(m0 + arow) * K + k0 + ak4];
    float4 bv = make_float4(0.f, 0.f, 0.f, 0.f);
    if (n0 + bn4 < N) bv = *(const float4*)&B[(long)(k0 + bkrow) * N + n0 + bn4];
    __syncthreads();
    As[ak4 + 0][arow] = av.x; As[ak4 + 1][arow] = av.y;
    As[ak4 + 2][arow] = av.z; As[ak4 + 3][arow] = av.w;
    *(float4*)&Bs[bkrow][bn4] = bv;
    __syncthreads();
#pragma unroll
    for (int kk = 0; kk < 16; ++kk) {
      float4 a = *(const float4*)&As[kk][tr];
      float4 bq = *(const float4*)&Bs[kk][tc];
      float ar[4] = {a.x, a.y, a.z, a.w};
      float br[4] = {bq.x, bq.y, bq.z, bq.w};
#pragma unroll
      for (int ii = 0; ii < 4; ++ii)
#pragma unroll
        for (int jj = 0; jj < 4; ++jj) acc[ii][jj] = fmaf(ar[ii], br[jj], acc[ii][jj]);
    }
  }
#pragma unroll
  for (int ii = 0; ii < 4; ++ii)
#pragma unroll
    for (int jj = 0; jj < 4; ++jj) {
      int n = n0 + tc + jj;
      if (n < N) {
        long idx = (long)(m0 + tr + ii) * N + n;
        C[idx] = ACC ? (C[idx] + acc[ii][jj]) : acc[ii][jj];
      }
    }
}

// ---------------------------------------------------------------------------
// Causal depthwise conv (within-chunk) + SiLU, all 4 variants
__global__ void k_conv(const float* __restrict__ xz, const float* __restrict__ cw,
                       const float* __restrict__ cb, float* __restrict__ xh) {
  long i = (long)blockIdx.x * 256 + threadIdx.x;  // 4*NT*Di
  int v = (int)(i >> 19);
  int r = (int)(i & 524287);
  int t = r >> 8, d = r & 255;
  int l = t & ((512 >> v) - 1);
  float acc = cb[d];
#pragma unroll
  for (int j = 0; j < 4; ++j) {
    int off = 3 - j;
    if (l - off >= 0) acc = fmaf(cw[d * 4 + j], xz[(long)(t - off) * 512 + d], acc);
  }
  xh[i] = acc / (1.f + expf(-acc));
}

// dt = softplus(dbl[:, :8] @ dt_w + dt_b), all variants
__global__ void k_dt(const float* __restrict__ dbl, const float* __restrict__ w,
                     const float* __restrict__ bias, float* __restrict__ dtv) {
  long i = (long)blockIdx.x * 256 + threadIdx.x;  // 4*NT*256
  int v = (int)(i >> 19);
  int r = (int)(i & 524287);
  int t = r >> 8, d = r & 255;
  const float* row = dbl + (long)v * NT * 136 + (long)t * 136;
  float s = bias[d];
#pragma unroll
  for (int rr = 0; rr < 8; ++rr) s = fmaf(row[rr], w[rr * 256 + d], s);
  dtv[i] = fmaxf(s, 0.f) + log1pf(expf(-fabsf(s)));
}

// Cm slices -> d_out[262144 + ...]
__global__ void k_cmcopy(const float* __restrict__ dbl, float* __restrict__ out) {
  int i = blockIdx.x * 256 + threadIdx.x;  // 4*NT*64
  int v = i >> 17;
  int r = i & 131071;
  int t = r >> 6, s = r & 63;
  out[262144 + i] = dbl[(long)v * NT * 136 + (long)t * 136 + 72 + s];
}

// ---------------------------------------------------------------------------
// Selective scan: one wave per (variant, batch', d); lane = state s.
__global__ __launch_bounds__(256) void k_scan(const float* __restrict__ dtv,
                                              const float* __restrict__ xh,
                                              const float* __restrict__ dbl,
                                              const float* __restrict__ A2,
                                              float* __restrict__ ys) {
  int lane = threadIdx.x & 63;
  int gwid = (blockIdx.x * 256 + threadIdx.x) >> 6;
  int v, base;
  if (gwid < 1024)      { v = 0; base = 0; }
  else if (gwid < 3072) { v = 1; base = 1024; }
  else if (gwid < 7168) { v = 2; base = 3072; }
  else                  { v = 3; base = 7168; }
  int local = gwid - base;
  int b = local >> 8, d = local & 255;
  int Lp = 512 >> v;
  const float* dtp = dtv + (long)v * NT * Di;
  const float* xhp = xh + (long)v * NT * Di;
  const float* dblp = dbl + (long)v * NT * 136;
  float* ysp = ys + (long)v * NT * Di + (long)((b << 8) + d) * Lp;
  float a2 = A2[d * 64 + lane];
  float h = 0.f, ybuf = 0.f;
  int t0 = b * Lp;
#pragma unroll 4
  for (int l = 0; l < Lp; ++l) {
    int t = t0 + l;
    float dt = dtp[(long)t * Di + d];
    float xv = xhp[(long)t * Di + d];
    float bm = dblp[(long)t * 136 + 8 + lane];
    float cm = dblp[(long)t * 136 + 72 + lane];
    float a = __builtin_amdgcn_exp2f(dt * a2);
    h = fmaf(a, h, dt * xv * bm);
    float p = h * cm;
#pragma unroll
    for (int off = 32; off; off >>= 1) p += __shfl_xor(p, off);
    if (lane == (l & 63)) ybuf = p;
    if ((l & 63) == 63) ysp[(l & ~63) + lane] = ybuf;
  }
}

// y = (ys + D*xh) summed over variants, * silu(z)
__global__ void k_yfull(const float* __restrict__ ys, const float* __restrict__ xh,
                        const float* __restrict__ xz, const float* __restrict__ Dp,
                        float* __restrict__ yacc) {
  int i = blockIdx.x * 256 + threadIdx.x;  // NT*Di
  int t = i >> 8, d = i & 255;
  float z = xz[(long)t * 512 + 256 + d];
  float sil = z / (1.f + expf(-z));
  float Dd = Dp[d];
  float s = 0.f;
#pragma unroll
  for (int v = 0; v < 4; ++v) {
    int Lp = 512 >> v;
    int b = t >> (9 - v);
    int l = t & (Lp - 1);
    float ysv = ys[(long)v * NT * Di + (long)((b << 8) + d) * Lp + l];
    float xhv = xh[(long)v * NT * Di + i];
    s += ysv + Dd * xhv;
  }
  yacc[i] = s * sil;
}

// ---------------------------------------------------------------------------
// batchnorm stats over 2048 tokens -> scale/shift per feature
__global__ __launch_bounds__(256) void k_bnstats(const float* __restrict__ h, int F,
                                                 const float* __restrict__ g,
                                                 const float* __restrict__ b,
                                                 float* __restrict__ scale,
                                                 float* __restrict__ shift) {
  int f = blockIdx.x;
  float s = 0.f, sq = 0.f;
  for (int t = threadIdx.x; t < NT; t += 256) {
    float v = h[(long)t * F + f];
    s += v; sq += v * v;
  }
#pragma unroll
  for (int off = 32; off; off >>= 1) { s += __shfl_xor(s, off); sq += __shfl_xor(sq, off); }
  __shared__ float red[2][4];
  int w = threadIdx.x >> 6;
  if ((threadIdx.x & 63) == 0) { red[0][w] = s; red[1][w] = sq; }
  __syncthreads();
  if (threadIdx.x == 0) {
    s = red[0][0] + red[0][1] + red[0][2] + red[0][3];
    sq = red[1][0] + red[1][1] + red[1][2] + red[1][3];
    float mu = s * (1.f / NT);
    float var = sq * (1.f / NT) - mu * mu;
    float sc = g[f] * rsqrtf(var + EPSF);
    scale[f] = sc;
    shift[f] = b[f] - mu * sc;
  }
}

__global__ void k_bnrelu(const float* __restrict__ h, const float* __restrict__ scale,
                         const float* __restrict__ shift, float* __restrict__ out) {
  int i = blockIdx.x * 256 + threadIdx.x;  // NT*Hh
  int f = i & 255;
  out[i] = fmaxf(fmaf(h[i], scale[f], shift[f]), 0.f);
}

// pointwise complex diag op + relu (in place)
__global__ void k_freq(float* __restrict__ Xr, float* __restrict__ Xi,
                       const float* __restrict__ rd, const float* __restrict__ idg,
                       const float* __restrict__ rb, const float* __restrict__ ib) {
  int i = blockIdx.x * 256 + threadIdx.x;  // NT*Hh
  int f = i & 255;
  float a = Xr[i], b2 = Xi[i];
  float xr = fmaxf(a * rd[f] - b2 * idg[f] + rb[f], 0.f);
  float xi = fmaxf(b2 * rd[f] + a * idg[f] + ib[f], 0.f);
  Xr[i] = xr;
  Xi[i] = xi;
}

__global__ void k_final(const float* __restrict__ xo, const float* __restrict__ f2,
                        const float* __restrict__ scale, const float* __restrict__ shift,
                        float* __restrict__ out) {
  int i = blockIdx.x * 256 + threadIdx.x;  // NT*Dm
  int c = i & 127;
  out[i] = xo[i] + fmaf(f2[i], scale[c], shift[c]);
}

// ---------------------------------------------------------------------------
extern "C" void kernel_launch(void* const* d_in, const int* in_sizes, int n_in,
                              void* d_out, int out_size, void* d_ws, size_t ws_size,
                              hipStream_t stream) {
  const float* x         = (const float*)d_in[0];
  const float* ln_w      = (const float*)d_in[1];
  const float* ln_b      = (const float*)d_in[2];
  const float* in_proj_w = (const float*)d_in[3];
  const float* conv_w    = (const float*)d_in[4];
  const float* conv_b    = (const float*)d_in[5];
  const float* x_proj_w  = (const float*)d_in[6];
  const float* dt_proj_w = (const float*)d_in[7];
  const float* dt_proj_b = (const float*)d_in[8];
  const float* A_log     = (const float*)d_in[9];
  const float* D_param   = (const float*)d_in[10];
  const float* out_proj_w= (const float*)d_in[11];
  const float* n1w       = (const float*)d_in[12];
  const float* n1b       = (const float*)d_in[13];
  const float* n2w       = (const float*)d_in[14];
  const float* n2b       = (const float*)d_in[15];
  const float* fc1_w     = (const float*)d_in[16];
  const float* bn1_g     = (const float*)d_in[17];
  const float* bn1_b     = (const float*)d_in[18];
  const float* r_mat     = (const float*)d_in[19];
  const float* i_mat     = (const float*)d_in[20];
  const float* rb        = (const float*)d_in[21];
  const float* ib        = (const float*)d_in[22];
  const float* fc2_w     = (const float*)d_in[23];
  const float* bn2_g     = (const float*)d_in[24];
  const float* bn2_b     = (const float*)d_in[25];
  float* ws  = (float*)d_ws;
  float* out = (float*)d_out;

  k_tables<<<1024, 256, 0, stream>>>(A_log, fc1_w, fc2_w, r_mat, i_mat, ws);
  k_ln1<<<512, 256, 0, stream>>>(x, ln_w, ln_b, ws + O_XN);
  // xz = xn @ in_proj_w  (2048x512, K=128)
  k_gemm<false><<<dim3(8, 32, 1), 256, 0, stream>>>(ws + O_XN, in_proj_w, ws + O_XZ,
                                                    NT, 512, 128, 0, 0, 0);
  k_conv<<<8192, 256, 0, stream>>>(ws + O_XZ, conv_w, conv_b, ws + O_XH);
  // dbl_v = xh_v @ x_proj_w  (2048x136, K=256) batched over 4 variants
  k_gemm<false><<<dim3(3, 32, 4), 256, 0, stream>>>(ws + O_XH, x_proj_w, ws + O_DBL,
                                                    NT, 136, 256,
                                                    (long)NT * Di, 0, (long)NT * 136);
  k_dt<<<8192, 256, 0, stream>>>(ws + O_DBL, dt_proj_w, dt_proj_b, ws + O_DT);
  k_cmcopy<<<2048, 256, 0, stream>>>(ws + O_DBL, out);
  k_scan<<<3840, 256, 0, stream>>>(ws + O_DT, ws + O_XH, ws + O_DBL, ws + O_A2, ws + O_YS);
  k_yfull<<<2048, 256, 0, stream>>>(ws + O_YS, ws + O_XH, ws + O_XZ, D_param, ws + O_YACC);
  // x_o = yacc @ out_proj_w  (2048x128, K=256)
  k_gemm<false><<<dim3(2, 32, 1), 256, 0, stream>>>(ws + O_YACC, out_proj_w, ws + O_XO1,
                                                    NT, 128, 256, 0, 0, 0);
  k_lndbl<<<512, 256, 0, stream>>>(x, ws + O_XO1, n1w, n1b, n2w, n2b, ws + O_XO, ws + O_LN2);
  // h1 = ln2 @ fc1t  (2048x256, K=128)
  k_gemm<false><<<dim3(4, 32, 1), 256, 0, stream>>>(ws + O_LN2, ws + O_FC1T, ws + O_H1,
                                                    NT, 256, 128, 0, 0, 0);
  k_bnstats<<<256, 256, 0, stream>>>(ws + O_H1, 256, bn1_g, bn1_b, ws + O_ST1, ws + O_ST1 + 256);
  k_bnrelu<<<2048, 256, 0, stream>>>(ws + O_H1, ws + O_ST1, ws + O_ST1 + 256, ws + O_H1N);
  // forward DFT: Xr = Ctab@Hb, Xi = Stab@Hb  (M=512,N=256,K=512, batch 4)
  k_gemm<false><<<dim3(4, 8, 4), 256, 0, stream>>>(ws + O_CTAB, ws + O_H1N, ws + O_XR,
                                                   512, 256, 512, 0, 131072L, 131072L);
  k_gemm<false><<<dim3(4, 8, 4), 256, 0, stream>>>(ws + O_STAB, ws + O_H1N, ws + O_XI,
                                                   512, 256, 512, 0, 131072L, 131072L);
  k_freq<<<2048, 256, 0, stream>>>(ws + O_XR, ws + O_XI, ws + O_RD, ws + O_IDG, rb, ib);
  // inverse DFT (real part): H2 = Ctab@xr + Stab@xi
  k_gemm<false><<<dim3(4, 8, 4), 256, 0, stream>>>(ws + O_CTAB, ws + O_XR, ws + O_H2,
                                                   512, 256, 512, 0, 131072L, 131072L);
  k_gemm<true><<<dim3(4, 8, 4), 256, 0, stream>>>(ws + O_STAB, ws + O_XI, ws + O_H2,
                                                  512, 256, 512, 0, 131072L, 131072L);
  // f2 = H2 @ fc2t  (2048x128, K=256)
  k_gemm<false><<<dim3(2, 32, 1), 256, 0, stream>>>(ws + O_H2, ws + O_FC2T, ws + O_F2,
                                                    NT, 128, 256, 0, 0, 0);
  k_bnstats<<<128, 256, 0, stream>>>(ws + O_F2, 128, bn2_g, bn2_b, ws + O_ST2, ws + O_ST2 + 128);
  k_final<<<1024, 256, 0, stream>>>(ws + O_XO, ws + O_F2, ws + O_ST2, ws + O_ST2 + 128, out);
}

// Round 3
// 491.877 us; speedup vs baseline: 1.2568x; 1.2568x over previous
//
#include <hip/hip_runtime.h>
#include <math.h>

// ---------------------------------------------------------------------------
// SABlock_CrossMamba: 4x mamba variants (k=1,2,4,8) + LN residuals + freq-FFN
// fp32 throughout. DFT via mod-512 cos table lookups.
// R2b: writelane -> cndmask (builtin unavailable); DPP wave reduce; transposed
// dt/dx with readlane broadcast; merged DFT GEMMs.
// ---------------------------------------------------------------------------

constexpr int Bt = 4, Lt = 512, Dm = 128, Di = 256, Sn = 64, Rr = 8, Hh = 256;
constexpr int NT = Bt * Lt;            // 2048 tokens
constexpr float EPSF = 1e-5f;
constexpr float LOG2E = 1.4426950408889634f;
constexpr float ISQ512 = 0.04419417382415922f;  // 1/sqrt(512)

// ws layout (float offsets)
constexpr long O_COS  = 0;                        // 512
constexpr long O_CS2  = 512;                      // 1024*512 (fwd DFT [C;S])
constexpr long O_CSI  = O_CS2 + 524288;           // 512*1024 (inv DFT [C|S])
constexpr long O_A2   = O_CSI + 524288;           // 256*64
constexpr long O_FC1T = O_A2 + 16384;             // 128*256
constexpr long O_FC2T = O_FC1T + 32768;           // 256*128
constexpr long O_RD   = O_FC2T + 32768;           // 256
constexpr long O_IDG  = O_RD + 256;               // 256
constexpr long O_XN   = O_IDG + 256;              // NT*128
constexpr long O_XZ   = O_XN + 262144;            // NT*512
constexpr long O_XH   = O_XZ + 1048576;           // 4*NT*256
constexpr long O_DBL  = O_XH + 2097152;           // 4*NT*136
constexpr long O_DTT  = O_DBL + 1114112;          // 4*256*2048 (dt, [v][d][t])
constexpr long O_YS   = O_DTT + 2097152;          // 4*NT*256
constexpr long O_YACC = O_YS + 2097152;           // NT*256
constexpr long O_XO1  = O_YACC + 524288;          // NT*128
constexpr long O_XO   = O_XO1 + 262144;           // NT*128
constexpr long O_LN2  = O_XO + 262144;            // NT*128
constexpr long O_H1   = O_LN2 + 262144;           // NT*256
constexpr long O_H1N  = O_H1 + 524288;            // NT*256
constexpr long O_XRI  = O_H1N + 524288;           // 4*1024*256 ([Xr;Xi] per b)
constexpr long O_H2   = O_XRI + 1048576;          // NT*256
constexpr long O_F2   = O_H2 + 524288;            // NT*128
constexpr long O_ST1  = O_F2 + 262144;            // 512
constexpr long O_ST2  = O_ST1 + 512;              // 384
// DXT (dt*xh, [v][d][t]) aliases H1..XRI — disjoint lifetime (dtx->scan only)
constexpr long O_DXT  = O_H1;                     // 2097152 = H1+H1N+XRI

// ---------------------------------------------------------------------------
__global__ void k_costab(float* __restrict__ ws) {
  int m = threadIdx.x;
  ws[O_COS + m]       = cosf((float)m * (6.283185307179586f / 512.0f)) * ISQ512;
  ws[O_COS + m + 256] = cosf((float)(m + 256) * (6.283185307179586f / 512.0f)) * ISQ512;
}

__global__ void k_tables(const float* __restrict__ A_log,
                         const float* __restrict__ fc1_w,
                         const float* __restrict__ fc2_w,
                         const float* __restrict__ r_mat,
                         const float* __restrict__ i_mat,
                         float* __restrict__ ws) {
  const float* ct = ws + O_COS;
  int i = blockIdx.x * 256 + threadIdx.x;   // covers 1048576
  if (i < 524288) {          // CS2[r][n]: r<512 cos(rn), else -sin((r-512)n)
    int r = i >> 9, n = i & 511;
    float v;
    if (r < 512) v = ct[(r * n) & 511];
    else         v = -ct[((r - 512) * n + 384) & 511];
    ws[O_CS2 + i] = v;
  } else {                   // CSI[n][k']: k'<512 cos(nk'), else -sin(n(k'-512))
    int j = i - 524288;
    int n = j >> 10, kp = j & 1023;
    float v;
    if (kp < 512) v = ct[(n * kp) & 511];
    else          v = -ct[(n * (kp - 512) + 384) & 511];
    ws[O_CSI + j] = v;
  }
  if (i < 16384) ws[O_A2 + i] = -expf(A_log[i]) * LOG2E;
  if (i < 32768) {  // fc1t[c][h] = fc1_w[h][c]
    int c = i >> 8, h = i & 255;
    ws[O_FC1T + i] = fc1_w[h * 128 + c];
    int h2 = i >> 7, c2 = i & 127;  // fc2t[h][c] = fc2_w[c][h]
    ws[O_FC2T + i] = fc2_w[c2 * 256 + h2];
  }
  if (i < 256) {
    ws[O_RD + i] = r_mat[i * 256 + i];
    ws[O_IDG + i] = i_mat[i * 256 + i];
  }
}

// ---------------------------------------------------------------------------
// LayerNorm over D=128, one wave per token
__global__ void k_ln1(const float* __restrict__ x, const float* __restrict__ w,
                      const float* __restrict__ b, float* __restrict__ out) {
  int lane = threadIdx.x & 63;
  int t = (blockIdx.x * 256 + threadIdx.x) >> 6;
  float v0 = x[t * 128 + lane], v1 = x[t * 128 + 64 + lane];
  float s = v0 + v1, sq = v0 * v0 + v1 * v1;
#pragma unroll
  for (int off = 32; off; off >>= 1) { s += __shfl_xor(s, off); sq += __shfl_xor(sq, off); }
  float mu = s * (1.f / 128.f);
  float rstd = rsqrtf(sq * (1.f / 128.f) - mu * mu + EPSF);
  out[t * 128 + lane]      = (v0 - mu) * rstd * w[lane] + b[lane];
  out[t * 128 + 64 + lane] = (v1 - mu) * rstd * w[64 + lane] + b[64 + lane];
}

// xo = x + LN(x_o)*w1+b1 ; ln2 = LN(xo)*w2+b2
__global__ void k_lndbl(const float* __restrict__ x, const float* __restrict__ xo1,
                        const float* __restrict__ w1, const float* __restrict__ b1,
                        const float* __restrict__ w2, const float* __restrict__ b2,
                        float* __restrict__ xo, float* __restrict__ ln2) {
  int lane = threadIdx.x & 63;
  int t = (blockIdx.x * 256 + threadIdx.x) >> 6;
  float u0 = xo1[t * 128 + lane], u1 = xo1[t * 128 + 64 + lane];
  float s = u0 + u1, sq = u0 * u0 + u1 * u1;
#pragma unroll
  for (int off = 32; off; off >>= 1) { s += __shfl_xor(s, off); sq += __shfl_xor(sq, off); }
  float mu = s * (1.f / 128.f);
  float rstd = rsqrtf(sq * (1.f / 128.f) - mu * mu + EPSF);
  float a0 = x[t * 128 + lane]      + (u0 - mu) * rstd * w1[lane] + b1[lane];
  float a1 = x[t * 128 + 64 + lane] + (u1 - mu) * rstd * w1[64 + lane] + b1[64 + lane];
  xo[t * 128 + lane] = a0;
  xo[t * 128 + 64 + lane] = a1;
  s = a0 + a1; sq = a0 * a0 + a1 * a1;
#pragma unroll
  for (int off = 32; off; off >>= 1) { s += __shfl_xor(s, off); sq += __shfl_xor(sq, off); }
  mu = s * (1.f / 128.f);
  rstd = rsqrtf(sq * (1.f / 128.f) - mu * mu + EPSF);
  ln2[t * 128 + lane]      = (a0 - mu) * rstd * w2[lane] + b2[lane];
  ln2[t * 128 + 64 + lane] = (a1 - mu) * rstd * w2[64 + lane] + b2[64 + lane];
}

// ---------------------------------------------------------------------------
// Generic tiled fp32 GEMM: C = A@B. Row-major. M%64==0, K%16==0, N%4==0.
__global__ __launch_bounds__(256) void k_gemm(const float* __restrict__ A,
                                              const float* __restrict__ B,
                                              float* __restrict__ C,
                                              int M, int N, int K,
                                              long sA, long sB, long sC) {
  A += (long)blockIdx.z * sA;
  B += (long)blockIdx.z * sB;
  C += (long)blockIdx.z * sC;
  __shared__ float As[16][68];
  __shared__ float Bs[16][68];
  int tid = threadIdx.x;
  int m0 = blockIdx.y * 64, n0 = blockIdx.x * 64;
  int arow = tid >> 2, ak4 = (tid & 3) * 4;
  int bkrow = tid >> 4, bn4 = (tid & 15) * 4;
  int tr = (tid >> 4) * 4, tc = (tid & 15) * 4;
  float acc[4][4] = {};
  for (int k0 = 0; k0 < K; k0 += 16) {
    float4 av = *(const float4*)&A[(long)(m0 + arow) * K + k0 + ak4];
    float4 bv = make_float4(0.f, 0.f, 0.f, 0.f);
    if (n0 + bn4 < N) bv = *(const float4*)&B[(long)(k0 + bkrow) * N + n0 + bn4];
    __syncthreads();
    As[ak4 + 0][arow] = av.x; As[ak4 + 1][arow] = av.y;
    As[ak4 + 2][arow] = av.z; As[ak4 + 3][arow] = av.w;
    *(float4*)&Bs[bkrow][bn4] = bv;
    __syncthreads();
#pragma unroll
    for (int kk = 0; kk < 16; ++kk) {
      float4 a = *(const float4*)&As[kk][tr];
      float4 bq = *(const float4*)&Bs[kk][tc];
      float ar[4] = {a.x, a.y, a.z, a.w};
      float br[4] = {bq.x, bq.y, bq.z, bq.w};
#pragma unroll
      for (int ii = 0; ii < 4; ++ii)
#pragma unroll
        for (int jj = 0; jj < 4; ++jj) acc[ii][jj] = fmaf(ar[ii], br[jj], acc[ii][jj]);
    }
  }
#pragma unroll
  for (int ii = 0; ii < 4; ++ii)
#pragma unroll
    for (int jj = 0; jj < 4; ++jj) {
      int n = n0 + tc + jj;
      if (n < N) C[(long)(m0 + tr + ii) * N + n] = acc[ii][jj];
    }
}

// ---------------------------------------------------------------------------
// Causal depthwise conv (within-chunk) + SiLU, all 4 variants
__global__ void k_conv(const float* __restrict__ xz, const float* __restrict__ cw,
                       const float* __restrict__ cb, float* __restrict__ xh) {
  long i = (long)blockIdx.x * 256 + threadIdx.x;  // 4*NT*Di
  int v = (int)(i >> 19);
  int r = (int)(i & 524287);
  int t = r >> 8, d = r & 255;
  int l = t & ((512 >> v) - 1);
  float acc = cb[d];
#pragma unroll
  for (int j = 0; j < 4; ++j) {
    int off = 3 - j;
    if (l - off >= 0) acc = fmaf(cw[d * 4 + j], xz[(long)(t - off) * 512 + d], acc);
  }
  xh[i] = acc / (1.f + expf(-acc));
}

// ---------------------------------------------------------------------------
// dt/dx transposed producer + Cm output copy.
// grid (x=d-tile 4, y=t-tile 32, z=v 4), 256 threads.
__global__ __launch_bounds__(256) void k_dtx(const float* __restrict__ dbl,
                                             const float* __restrict__ xh,
                                             const float* __restrict__ w,
                                             const float* __restrict__ bias,
                                             float* __restrict__ DTT,
                                             float* __restrict__ DXT,
                                             float* __restrict__ outC) {
  __shared__ float r8T[8][64];    // dbl[:, :8] transposed
  __shared__ float xt[64][65];    // xh tile [t][d], odd stride
  __shared__ float wt[8][64];     // dt_proj_w tile
  int v = blockIdx.z, t0 = blockIdx.y * 64, d0 = blockIdx.x * 64;
  int j = threadIdx.x;
  if (j < 128) {
    int t = j >> 1, half = j & 1;
    float4 q = *(const float4*)&dbl[((long)v * NT + t0 + t) * 136 + half * 4];
    r8T[half * 4 + 0][t] = q.x; r8T[half * 4 + 1][t] = q.y;
    r8T[half * 4 + 2][t] = q.z; r8T[half * 4 + 3][t] = q.w;
  } else {
    int idx = j - 128;           // 128 threads: 8 rows x 16 float4
    int r = idx >> 4, dl4 = (idx & 15) * 4;
    float4 q = *(const float4*)&w[r * 256 + d0 + dl4];
    wt[r][dl4] = q.x; wt[r][dl4 + 1] = q.y; wt[r][dl4 + 2] = q.z; wt[r][dl4 + 3] = q.w;
  }
#pragma unroll
  for (int it = 0; it < 4; ++it) {
    int row = (j >> 4) + it * 16, col4 = (j & 15) * 4;
    float4 q = *(const float4*)&xh[((long)v * NT + t0 + row) * 256 + d0 + col4];
    xt[row][col4] = q.x; xt[row][col4 + 1] = q.y;
    xt[row][col4 + 2] = q.z; xt[row][col4 + 3] = q.w;
  }
  __syncthreads();
  int lane = j & 63, w4 = j >> 6;
#pragma unroll
  for (int k = 0; k < 16; ++k) {
    int dl = w4 * 16 + k, d = d0 + dl;
    float s = bias[d];
#pragma unroll
    for (int r = 0; r < 8; ++r) s = fmaf(r8T[r][lane], wt[r][dl], s);
    float dtv = fmaxf(s, 0.f) + log1pf(expf(-fabsf(s)));
    float dx = dtv * xt[lane][dl];
    long oi = ((long)(v * 256 + d)) * 2048 + t0 + lane;
    DTT[oi] = dtv;
    DXT[oi] = dx;
  }
  if (blockIdx.x == 0) {  // Cm -> out, once per (v, t-tile)
#pragma unroll
    for (int k2 = 0; k2 < 16; ++k2) {
      int idx = k2 * 256 + j;
      int tl = idx >> 6, s2 = idx & 63;
      outC[(long)v * 131072 + (long)(t0 + tl) * 64 + s2] =
          dbl[((long)v * NT + t0 + tl) * 136 + 72 + s2];
    }
  }
}

// ---------------------------------------------------------------------------
// VALU-only wave64 sum -> lane 63 (DPP row_shr + bcast adds)
template <int CTRL>
__device__ __forceinline__ float dpp_add(float x) {
  int t = __builtin_amdgcn_update_dpp(0, __float_as_int(x), CTRL, 0xF, 0xF, true);
  return x + __int_as_float(t);
}

// Selective scan: one wave per (variant, batch', d); lane = state s.
__global__ __launch_bounds__(256) void k_scan(const float* __restrict__ DTT,
                                              const float* __restrict__ DXT,
                                              const float* __restrict__ dbl,
                                              const float* __restrict__ A2,
                                              float* __restrict__ ys) {
  int lane = threadIdx.x & 63;
  int gwid = (blockIdx.x * 256 + threadIdx.x) >> 6;
  int v, base;
  if (gwid < 1024)      { v = 0; base = 0; }
  else if (gwid < 3072) { v = 1; base = 1024; }
  else if (gwid < 7168) { v = 2; base = 3072; }
  else                  { v = 3; base = 7168; }
  int local = gwid - base;
  int b = local >> 8, d = local & 255;
  int Lp = 512 >> v;
  int t0 = b * Lp;
  const float* dtrow = DTT + ((long)(v * 256 + d)) * 2048 + t0;
  const float* dxrow = DXT + ((long)(v * 256 + d)) * 2048 + t0;
  const float* dblp = dbl + ((long)v * NT + t0) * 136;
  float* ysp = ys + (long)v * NT * Di + (long)((b << 8) + d) * Lp;
  float a2 = A2[d * 64 + lane];
  float h = 0.f;
  for (int c = 0; c < Lp; c += 64) {
    float rdt = dtrow[c + lane];          // 64 steps of dt, one per lane
    float rdx = dxrow[c + lane];          // 64 steps of dt*xh
    const float* rowp = dblp + (long)c * 136;
    float ybuf = 0.f;
#pragma unroll
    for (int l2 = 0; l2 < 64; ++l2) {
      float sdt = __int_as_float(__builtin_amdgcn_readlane(__float_as_int(rdt), l2));
      float sdx = __int_as_float(__builtin_amdgcn_readlane(__float_as_int(rdx), l2));
      float bm = rowp[l2 * 136 + 8 + lane];
      float cm = rowp[l2 * 136 + 72 + lane];
      float a = __builtin_amdgcn_exp2f(sdt * a2);
      h = fmaf(a, h, sdx * bm);
      float p = h * cm;
      p = dpp_add<0x111>(p);   // row_shr:1
      p = dpp_add<0x112>(p);   // row_shr:2
      p = dpp_add<0x114>(p);   // row_shr:4
      p = dpp_add<0x118>(p);   // row_shr:8
      p = dpp_add<0x142>(p);   // row_bcast15
      p = dpp_add<0x143>(p);   // row_bcast31 -> lane63 = full sum
      float tot = __int_as_float(__builtin_amdgcn_readlane(__float_as_int(p), 63));
      if (lane == l2) ybuf = tot;   // v_cmp + v_cndmask (VALU)
    }
    ysp[c + lane] = ybuf;
  }
}

// y = (ys + D*xh) summed over variants, * silu(z)
__global__ void k_yfull(const float* __restrict__ ys, const float* __restrict__ xh,
                        const float* __restrict__ xz, const float* __restrict__ Dp,
                        float* __restrict__ yacc) {
  int i = blockIdx.x * 256 + threadIdx.x;  // NT*Di
  int t = i >> 8, d = i & 255;
  float z = xz[(long)t * 512 + 256 + d];
  float sil = z / (1.f + expf(-z));
  float Dd = Dp[d];
  float s = 0.f;
#pragma unroll
  for (int v = 0; v < 4; ++v) {
    int Lp = 512 >> v;
    int b = t >> (9 - v);
    int l = t & (Lp - 1);
    float ysv = ys[(long)v * NT * Di + (long)((b << 8) + d) * Lp + l];
    float xhv = xh[(long)v * NT * Di + i];
    s += ysv + Dd * xhv;
  }
  yacc[i] = s * sil;
}

// ---------------------------------------------------------------------------
__global__ __launch_bounds__(256) void k_bnstats(const float* __restrict__ h, int F,
                                                 const float* __restrict__ g,
                                                 const float* __restrict__ b,
                                                 float* __restrict__ scale,
                                                 float* __restrict__ shift) {
  int f = blockIdx.x;
  float s = 0.f, sq = 0.f;
  for (int t = threadIdx.x; t < NT; t += 256) {
    float v = h[(long)t * F + f];
    s += v; sq += v * v;
  }
#pragma unroll
  for (int off = 32; off; off >>= 1) { s += __shfl_xor(s, off); sq += __shfl_xor(sq, off); }
  __shared__ float red[2][4];
  int w = threadIdx.x >> 6;
  if ((threadIdx.x & 63) == 0) { red[0][w] = s; red[1][w] = sq; }
  __syncthreads();
  if (threadIdx.x == 0) {
    s = red[0][0] + red[0][1] + red[0][2] + red[0][3];
    sq = red[1][0] + red[1][1] + red[1][2] + red[1][3];
    float mu = s * (1.f / NT);
    float var = sq * (1.f / NT) - mu * mu;
    float sc = g[f] * rsqrtf(var + EPSF);
    scale[f] = sc;
    shift[f] = b[f] - mu * sc;
  }
}

__global__ void k_bnrelu(const float* __restrict__ h, const float* __restrict__ scale,
                         const float* __restrict__ shift, float* __restrict__ out) {
  int i = blockIdx.x * 256 + threadIdx.x;  // NT*Hh
  int f = i & 255;
  out[i] = fmaxf(fmaf(h[i], scale[f], shift[f]), 0.f);
}

// pointwise complex diag op + relu on XRI ([Xr(512);Xi(512)] x 256 per batch)
__global__ void k_freq(float* __restrict__ XRI,
                       const float* __restrict__ rd, const float* __restrict__ idg,
                       const float* __restrict__ rb, const float* __restrict__ ib) {
  int i = blockIdx.x * 256 + threadIdx.x;  // 4*512*256
  int b = i >> 17, rem = i & 131071;
  int n = rem & 255;
  long base = (long)b * 262144 + rem;
  float a = XRI[base], b2 = XRI[base + 131072];
  XRI[base]          = fmaxf(a * rd[n] - b2 * idg[n] + rb[n], 0.f);
  XRI[base + 131072] = fmaxf(b2 * rd[n] + a * idg[n] + ib[n], 0.f);
}

__global__ void k_final(const float* __restrict__ xo, const float* __restrict__ f2,
                        const float* __restrict__ scale, const float* __restrict__ shift,
                        float* __restrict__ out) {
  int i = blockIdx.x * 256 + threadIdx.x;  // NT*Dm
  int c = i & 127;
  out[i] = xo[i] + fmaf(f2[i], scale[c], shift[c]);
}

// ---------------------------------------------------------------------------
extern "C" void kernel_launch(void* const* d_in, const int* in_sizes, int n_in,
                              void* d_out, int out_size, void* d_ws, size_t ws_size,
                              hipStream_t stream) {
  const float* x         = (const float*)d_in[0];
  const float* ln_w      = (const float*)d_in[1];
  const float* ln_b      = (const float*)d_in[2];
  const float* in_proj_w = (const float*)d_in[3];
  const float* conv_w    = (const float*)d_in[4];
  const float* conv_b    = (const float*)d_in[5];
  const float* x_proj_w  = (const float*)d_in[6];
  const float* dt_proj_w = (const float*)d_in[7];
  const float* dt_proj_b = (const float*)d_in[8];
  const float* A_log     = (const float*)d_in[9];
  const float* D_param   = (const float*)d_in[10];
  const float* out_proj_w= (const float*)d_in[11];
  const float* n1w       = (const float*)d_in[12];
  const float* n1b       = (const float*)d_in[13];
  const float* n2w       = (const float*)d_in[14];
  const float* n2b       = (const float*)d_in[15];
  const float* fc1_w     = (const float*)d_in[16];
  const float* bn1_g     = (const float*)d_in[17];
  const float* bn1_b     = (const float*)d_in[18];
  const float* r_mat     = (const float*)d_in[19];
  const float* i_mat     = (const float*)d_in[20];
  const float* rb        = (const float*)d_in[21];
  const float* ib        = (const float*)d_in[22];
  const float* fc2_w     = (const float*)d_in[23];
  const float* bn2_g     = (const float*)d_in[24];
  const float* bn2_b     = (const float*)d_in[25];
  float* ws  = (float*)d_ws;
  float* out = (float*)d_out;

  k_costab<<<1, 256, 0, stream>>>(ws);
  k_tables<<<4096, 256, 0, stream>>>(A_log, fc1_w, fc2_w, r_mat, i_mat, ws);
  k_ln1<<<512, 256, 0, stream>>>(x, ln_w, ln_b, ws + O_XN);
  // xz = xn @ in_proj_w  (2048x512, K=128)
  k_gemm<<<dim3(8, 32, 1), 256, 0, stream>>>(ws + O_XN, in_proj_w, ws + O_XZ,
                                             NT, 512, 128, 0, 0, 0);
  k_conv<<<8192, 256, 0, stream>>>(ws + O_XZ, conv_w, conv_b, ws + O_XH);
  // dbl_v = xh_v @ x_proj_w  (2048x136, K=256) batched over 4 variants
  k_gemm<<<dim3(3, 32, 4), 256, 0, stream>>>(ws + O_XH, x_proj_w, ws + O_DBL,
                                             NT, 136, 256,
                                             (long)NT * Di, 0, (long)NT * 136);
  k_dtx<<<dim3(4, 32, 4), 256, 0, stream>>>(ws + O_DBL, ws + O_XH, dt_proj_w,
                                            dt_proj_b, ws + O_DTT, ws + O_DXT,
                                            out + 262144);
  k_scan<<<3840, 256, 0, stream>>>(ws + O_DTT, ws + O_DXT, ws + O_DBL,
                                   ws + O_A2, ws + O_YS);
  k_yfull<<<2048, 256, 0, stream>>>(ws + O_YS, ws + O_XH, ws + O_XZ, D_param,
                                    ws + O_YACC);
  // x_o = yacc @ out_proj_w  (2048x128, K=256)
  k_gemm<<<dim3(2, 32, 1), 256, 0, stream>>>(ws + O_YACC, out_proj_w, ws + O_XO1,
                                             NT, 128, 256, 0, 0, 0);
  k_lndbl<<<512, 256, 0, stream>>>(x, ws + O_XO1, n1w, n1b, n2w, n2b,
                                   ws + O_XO, ws + O_LN2);
  // h1 = ln2 @ fc1t  (2048x256, K=128)
  k_gemm<<<dim3(4, 32, 1), 256, 0, stream>>>(ws + O_LN2, ws + O_FC1T, ws + O_H1,
                                             NT, 256, 128, 0, 0, 0);
  k_bnstats<<<256, 256, 0, stream>>>(ws + O_H1, 256, bn1_g, bn1_b,
                                     ws + O_ST1, ws + O_ST1 + 256);
  k_bnrelu<<<2048, 256, 0, stream>>>(ws + O_H1, ws + O_ST1, ws + O_ST1 + 256,
                                     ws + O_H1N);
  // forward DFT: [Xr;Xi]_b = CS2(1024x512) @ H1N_b(512x256) — one launch
  k_gemm<<<dim3(4, 16, 4), 256, 0, stream>>>(ws + O_CS2, ws + O_H1N, ws + O_XRI,
                                             1024, 256, 512, 0, 131072L, 262144L);
  k_freq<<<2048, 256, 0, stream>>>(ws + O_XRI, ws + O_RD, ws + O_IDG, rb, ib);
  // inverse DFT real part: H2_b = CSI(512x1024) @ [xr;xi]_b — one launch
  k_gemm<<<dim3(4, 8, 4), 256, 0, stream>>>(ws + O_CSI, ws + O_XRI, ws + O_H2,
                                            512, 256, 1024, 0, 262144L, 131072L);
  // f2 = H2 @ fc2t  (2048x128, K=256)
  k_gemm<<<dim3(2, 32, 1), 256, 0, stream>>>(ws + O_H2, ws + O_FC2T, ws + O_F2,
                                             NT, 128, 256, 0, 0, 0);
  k_bnstats<<<128, 256, 0, stream>>>(ws + O_F2, 128, bn2_g, bn2_b,
                                     ws + O_ST2, ws + O_ST2 + 128);
  k_final<<<1024, 256, 0, stream>>>(ws + O_XO, ws + O_F2, ws + O_ST2,
                                    ws + O_ST2 + 128, out);
}

// Round 4
// 330.012 us; speedup vs baseline: 1.8732x; 1.4905x over previous
//
#include <hip/hip_runtime.h>
#include <hip/hip_bf16.h>
#include <math.h>

// ---------------------------------------------------------------------------
// SABlock_CrossMamba. R4: (a) scan software-pipelined register prefetch;
// (b) FFN-path GEMMs (h1, fwd/inv DFT, f2) -> bf16 MFMA 16x16x32;
// mamba-path GEMMs stay fp32.
// ---------------------------------------------------------------------------

constexpr int NT = 2048;
constexpr int Di = 256;
constexpr float EPSF = 1e-5f;
constexpr float LOG2E = 1.4426950408889634f;
constexpr float ISQ512 = 0.04419417382415922f;  // 1/sqrt(512)

typedef __attribute__((ext_vector_type(8))) short short8;
typedef __attribute__((ext_vector_type(4))) float f32x4;

// ws layout (float offsets, all 16B-aligned)
constexpr long O_COS   = 0;                       // 512
constexpr long O_CS2B  = 512;                     // bf16 1024x512 -> 262144 fl
constexpr long O_CSIB  = 262656;                  // bf16 512x1024 -> 262144 fl
constexpr long O_A2    = 524800;                  // 16384
constexpr long O_FC1B  = 541184;                  // bf16 256x128 -> 16384 fl
constexpr long O_FC2B  = 557568;                  // bf16 128x256 -> 16384 fl
constexpr long O_RD    = 573952;                  // 256
constexpr long O_IDG   = 574208;                  // 256
constexpr long O_XN    = 574464;                  // 262144
constexpr long O_XZ    = 836608;                  // 1048576
constexpr long O_XH    = 1885184;                 // 2097152
constexpr long O_DBL   = 3982336;                 // 1114112
constexpr long O_DTT   = 5096448;                 // 2097152
constexpr long O_YS    = 7193600;                 // 2097152
constexpr long O_YACC  = 9290752;                 // 524288
constexpr long O_XO1   = 9815040;                 // 262144
constexpr long O_XO    = 10077184;                // 262144
constexpr long O_LN2B  = 10339328;                // bf16 2048x128 -> 65536 fl
constexpr long O_H1    = 10404864;                // 524288 (fp32)
constexpr long O_H1NTB = 10929152;                // bf16 4x256x512 -> 262144 fl
constexpr long O_XRI   = 11191296;                // 1048576 (fp32)
constexpr long O_XRITB = 12239872;                // bf16 4x256x1024 -> 524288 fl
constexpr long O_H2B   = 12764160;                // bf16 2048x256 -> 262144 fl
constexpr long O_F2    = 13026304;                // 262144
constexpr long O_ST1   = 13288448;                // 512
constexpr long O_ST2   = 13288960;                // 384
// DXT aliases [H1 .. XRITB) — lifetime: k_dtx -> k_scan only; those regions
// are written only after the scan.
constexpr long O_DXT   = O_H1;                    // 2097152 floats

__device__ __forceinline__ ushort bf16bits(float v) {
  __hip_bfloat16 h = __float2bfloat16(v);
  return *(ushort*)&h;
}

// ---------------------------------------------------------------------------
__global__ void k_costab(float* __restrict__ ws) {
  int m = threadIdx.x;
  ws[O_COS + m]       = cosf((float)m * (6.283185307179586f / 512.0f)) * ISQ512;
  ws[O_COS + m + 256] = cosf((float)(m + 256) * (6.283185307179586f / 512.0f)) * ISQ512;
}

__global__ void k_tables(const float* __restrict__ A_log,
                         const float* __restrict__ fc1_w,
                         const float* __restrict__ fc2_w,
                         const float* __restrict__ r_mat,
                         const float* __restrict__ i_mat,
                         float* __restrict__ ws) {
  const float* ct = ws + O_COS;
  __hip_bfloat16* cs2b = (__hip_bfloat16*)(ws + O_CS2B);
  __hip_bfloat16* csib = (__hip_bfloat16*)(ws + O_CSIB);
  int i = blockIdx.x * 256 + threadIdx.x;   // 1048576 threads
  if (i < 524288) {          // CS2[r][n]: r<512 cos(rn), else -sin((r-512)n)
    int r = i >> 9, n = i & 511;
    float v;
    if (r < 512) v = ct[(r * n) & 511];
    else         v = -ct[((r - 512) * n + 384) & 511];
    cs2b[i] = __float2bfloat16(v);
  } else {                   // CSI[n][kp]: kp<512 cos(n*kp), else -sin(n(kp-512))
    int j = i - 524288;
    int n = j >> 10, kp = j & 1023;
    float v;
    if (kp < 512) v = ct[(n * kp) & 511];
    else          v = -ct[(n * (kp - 512) + 384) & 511];
    csib[j] = __float2bfloat16(v);
  }
  if (i < 16384) ws[O_A2 + i] = -expf(A_log[i]) * LOG2E;
  if (i < 32768) {
    ((__hip_bfloat16*)(ws + O_FC1B))[i] = __float2bfloat16(fc1_w[i]);  // Bt for h1
    ((__hip_bfloat16*)(ws + O_FC2B))[i] = __float2bfloat16(fc2_w[i]);  // Bt for f2
  }
  if (i < 256) {
    ws[O_RD + i] = r_mat[i * 256 + i];
    ws[O_IDG + i] = i_mat[i * 256 + i];
  }
}

// ---------------------------------------------------------------------------
__global__ void k_ln1(const float* __restrict__ x, const float* __restrict__ w,
                      const float* __restrict__ b, float* __restrict__ out) {
  int lane = threadIdx.x & 63;
  int t = (blockIdx.x * 256 + threadIdx.x) >> 6;
  float v0 = x[t * 128 + lane], v1 = x[t * 128 + 64 + lane];
  float s = v0 + v1, sq = v0 * v0 + v1 * v1;
#pragma unroll
  for (int off = 32; off; off >>= 1) { s += __shfl_xor(s, off); sq += __shfl_xor(sq, off); }
  float mu = s * (1.f / 128.f);
  float rstd = rsqrtf(sq * (1.f / 128.f) - mu * mu + EPSF);
  out[t * 128 + lane]      = (v0 - mu) * rstd * w[lane] + b[lane];
  out[t * 128 + 64 + lane] = (v1 - mu) * rstd * w[64 + lane] + b[64 + lane];
}

// xo = x + LN(x_o)*w1+b1 ; ln2b = bf16(LN(xo)*w2+b2)
__global__ void k_lndbl(const float* __restrict__ x, const float* __restrict__ xo1,
                        const float* __restrict__ w1, const float* __restrict__ b1,
                        const float* __restrict__ w2, const float* __restrict__ b2,
                        float* __restrict__ xo, __hip_bfloat16* __restrict__ ln2b) {
  int lane = threadIdx.x & 63;
  int t = (blockIdx.x * 256 + threadIdx.x) >> 6;
  float u0 = xo1[t * 128 + lane], u1 = xo1[t * 128 + 64 + lane];
  float s = u0 + u1, sq = u0 * u0 + u1 * u1;
#pragma unroll
  for (int off = 32; off; off >>= 1) { s += __shfl_xor(s, off); sq += __shfl_xor(sq, off); }
  float mu = s * (1.f / 128.f);
  float rstd = rsqrtf(sq * (1.f / 128.f) - mu * mu + EPSF);
  float a0 = x[t * 128 + lane]      + (u0 - mu) * rstd * w1[lane] + b1[lane];
  float a1 = x[t * 128 + 64 + lane] + (u1 - mu) * rstd * w1[64 + lane] + b1[64 + lane];
  xo[t * 128 + lane] = a0;
  xo[t * 128 + 64 + lane] = a1;
  s = a0 + a1; sq = a0 * a0 + a1 * a1;
#pragma unroll
  for (int off = 32; off; off >>= 1) { s += __shfl_xor(s, off); sq += __shfl_xor(sq, off); }
  mu = s * (1.f / 128.f);
  rstd = rsqrtf(sq * (1.f / 128.f) - mu * mu + EPSF);
  ln2b[t * 128 + lane]      = __float2bfloat16((a0 - mu) * rstd * w2[lane] + b2[lane]);
  ln2b[t * 128 + 64 + lane] = __float2bfloat16((a1 - mu) * rstd * w2[64 + lane] + b2[64 + lane]);
}

// ---------------------------------------------------------------------------
// fp32 tiled GEMM (mamba path): C = A@B row-major. M%64==0, K%16==0.
__global__ __launch_bounds__(256) void k_gemm(const float* __restrict__ A,
                                              const float* __restrict__ B,
                                              float* __restrict__ C,
                                              int M, int N, int K,
                                              long sA, long sB, long sC) {
  A += (long)blockIdx.z * sA;
  B += (long)blockIdx.z * sB;
  C += (long)blockIdx.z * sC;
  __shared__ float As[16][68];
  __shared__ float Bs[16][68];
  int tid = threadIdx.x;
  int m0 = blockIdx.y * 64, n0 = blockIdx.x * 64;
  int arow = tid >> 2, ak4 = (tid & 3) * 4;
  int bkrow = tid >> 4, bn4 = (tid & 15) * 4;
  int tr = (tid >> 4) * 4, tc = (tid & 15) * 4;
  float acc[4][4] = {};
  for (int k0 = 0; k0 < K; k0 += 16) {
    float4 av = *(const float4*)&A[(long)(m0 + arow) * K + k0 + ak4];
    float4 bv = make_float4(0.f, 0.f, 0.f, 0.f);
    if (n0 + bn4 < N) bv = *(const float4*)&B[(long)(k0 + bkrow) * N + n0 + bn4];
    __syncthreads();
    As[ak4 + 0][arow] = av.x; As[ak4 + 1][arow] = av.y;
    As[ak4 + 2][arow] = av.z; As[ak4 + 3][arow] = av.w;
    *(float4*)&Bs[bkrow][bn4] = bv;
    __syncthreads();
#pragma unroll
    for (int kk = 0; kk < 16; ++kk) {
      float4 a = *(const float4*)&As[kk][tr];
      float4 bq = *(const float4*)&Bs[kk][tc];
      float ar[4] = {a.x, a.y, a.z, a.w};
      float br[4] = {bq.x, bq.y, bq.z, bq.w};
#pragma unroll
      for (int ii = 0; ii < 4; ++ii)
#pragma unroll
        for (int jj = 0; jj < 4; ++jj) acc[ii][jj] = fmaf(ar[ii], br[jj], acc[ii][jj]);
    }
  }
#pragma unroll
  for (int ii = 0; ii < 4; ++ii)
#pragma unroll
    for (int jj = 0; jj < 4; ++jj) {
      int n = n0 + tc + jj;
      if (n < N) C[(long)(m0 + tr + ii) * N + n] = acc[ii][jj];
    }
}

// ---------------------------------------------------------------------------
// bf16 MFMA GEMM: C = A @ Bt^T. A: MxK bf16 row-major; Bt: NxK bf16 row-major.
// M%64==0, N%64==0, K%32==0. Output fp32 or bf16 row-major MxN.
template <bool OUTBF16>
__global__ __launch_bounds__(256) void k_gmfma(const ushort* __restrict__ A,
                                               const ushort* __restrict__ Bt,
                                               void* __restrict__ Cv,
                                               int M, int N, int K,
                                               long sA, long sBt, long sC) {
  A += (long)blockIdx.z * sA;
  Bt += (long)blockIdx.z * sBt;
  int lane = threadIdx.x & 63, wid = threadIdx.x >> 6;
  int m0 = blockIdx.y * 64 + wid * 16, n0 = blockIdx.x * 64;
  const ushort* arow = A + (long)(m0 + (lane & 15)) * K + (lane >> 4) * 8;
  const ushort* brow = Bt + (long)(n0 + (lane & 15)) * K + (lane >> 4) * 8;
  f32x4 acc0 = {0.f, 0.f, 0.f, 0.f}, acc1 = acc0, acc2 = acc0, acc3 = acc0;
#pragma unroll 4
  for (int k0 = 0; k0 < K; k0 += 32) {
    short8 av = *(const short8*)(arow + k0);
    short8 b0 = *(const short8*)(brow + k0);
    short8 b1 = *(const short8*)(brow + 16L * K + k0);
    short8 b2 = *(const short8*)(brow + 32L * K + k0);
    short8 b3 = *(const short8*)(brow + 48L * K + k0);
    acc0 = __builtin_amdgcn_mfma_f32_16x16x32_bf16(av, b0, acc0, 0, 0, 0);
    acc1 = __builtin_amdgcn_mfma_f32_16x16x32_bf16(av, b1, acc1, 0, 0, 0);
    acc2 = __builtin_amdgcn_mfma_f32_16x16x32_bf16(av, b2, acc2, 0, 0, 0);
    acc3 = __builtin_amdgcn_mfma_f32_16x16x32_bf16(av, b3, acc3, 0, 0, 0);
  }
  int r0 = (lane >> 4) * 4, c0 = lane & 15;
#pragma unroll
  for (int j = 0; j < 4; ++j) {
    long row = m0 + r0 + j;
    float v[4] = {acc0[j], acc1[j], acc2[j], acc3[j]};
    if (OUTBF16) {
      __hip_bfloat16* C = (__hip_bfloat16*)Cv + blockIdx.z * sC;
#pragma unroll
      for (int c = 0; c < 4; ++c) C[row * N + n0 + c * 16 + c0] = __float2bfloat16(v[c]);
    } else {
      float* C = (float*)Cv + blockIdx.z * sC;
#pragma unroll
      for (int c = 0; c < 4; ++c) C[row * N + n0 + c * 16 + c0] = v[c];
    }
  }
}

// ---------------------------------------------------------------------------
__global__ void k_conv(const float* __restrict__ xz, const float* __restrict__ cw,
                       const float* __restrict__ cb, float* __restrict__ xh) {
  long i = (long)blockIdx.x * 256 + threadIdx.x;  // 4*NT*Di
  int v = (int)(i >> 19);
  int r = (int)(i & 524287);
  int t = r >> 8, d = r & 255;
  int l = t & ((512 >> v) - 1);
  float acc = cb[d];
#pragma unroll
  for (int j = 0; j < 4; ++j) {
    int off = 3 - j;
    if (l - off >= 0) acc = fmaf(cw[d * 4 + j], xz[(long)(t - off) * 512 + d], acc);
  }
  xh[i] = acc / (1.f + expf(-acc));
}

// ---------------------------------------------------------------------------
__global__ __launch_bounds__(256) void k_dtx(const float* __restrict__ dbl,
                                             const float* __restrict__ xh,
                                             const float* __restrict__ w,
                                             const float* __restrict__ bias,
                                             float* __restrict__ DTT,
                                             float* __restrict__ DXT,
                                             float* __restrict__ outC) {
  __shared__ float r8T[8][64];
  __shared__ float xt[64][65];
  __shared__ float wt[8][64];
  int v = blockIdx.z, t0 = blockIdx.y * 64, d0 = blockIdx.x * 64;
  int j = threadIdx.x;
  if (j < 128) {
    int t = j >> 1, half = j & 1;
    float4 q = *(const float4*)&dbl[((long)v * NT + t0 + t) * 136 + half * 4];
    r8T[half * 4 + 0][t] = q.x; r8T[half * 4 + 1][t] = q.y;
    r8T[half * 4 + 2][t] = q.z; r8T[half * 4 + 3][t] = q.w;
  } else {
    int idx = j - 128;
    int r = idx >> 4, dl4 = (idx & 15) * 4;
    float4 q = *(const float4*)&w[r * 256 + d0 + dl4];
    wt[r][dl4] = q.x; wt[r][dl4 + 1] = q.y; wt[r][dl4 + 2] = q.z; wt[r][dl4 + 3] = q.w;
  }
#pragma unroll
  for (int it = 0; it < 4; ++it) {
    int row = (j >> 4) + it * 16, col4 = (j & 15) * 4;
    float4 q = *(const float4*)&xh[((long)v * NT + t0 + row) * 256 + d0 + col4];
    xt[row][col4] = q.x; xt[row][col4 + 1] = q.y;
    xt[row][col4 + 2] = q.z; xt[row][col4 + 3] = q.w;
  }
  __syncthreads();
  int lane = j & 63, w4 = j >> 6;
#pragma unroll
  for (int k = 0; k < 16; ++k) {
    int dl = w4 * 16 + k, d = d0 + dl;
    float s = bias[d];
#pragma unroll
    for (int r = 0; r < 8; ++r) s = fmaf(r8T[r][lane], wt[r][dl], s);
    float dtv = fmaxf(s, 0.f) + log1pf(expf(-fabsf(s)));
    float dx = dtv * xt[lane][dl];
    long oi = ((long)(v * 256 + d)) * 2048 + t0 + lane;
    DTT[oi] = dtv;
    DXT[oi] = dx;
  }
  if (blockIdx.x == 0) {
#pragma unroll
    for (int k2 = 0; k2 < 16; ++k2) {
      int idx = k2 * 256 + j;
      int tl = idx >> 6, s2 = idx & 63;
      outC[(long)v * 131072 + (long)(t0 + tl) * 64 + s2] =
          dbl[((long)v * NT + t0 + tl) * 136 + 72 + s2];
    }
  }
}

// ---------------------------------------------------------------------------
template <int CTRL>
__device__ __forceinline__ float dpp_add(float x) {
  int t = __builtin_amdgcn_update_dpp(0, __float_as_int(x), CTRL, 0xF, 0xF, true);
  return x + __int_as_float(t);
}

// Selective scan, software-pipelined: 2-buffer x 8-step register prefetch.
__global__ __launch_bounds__(256) void k_scan(const float* __restrict__ DTT,
                                              const float* __restrict__ DXT,
                                              const float* __restrict__ dbl,
                                              const float* __restrict__ A2,
                                              float* __restrict__ ys) {
  int lane = threadIdx.x & 63;
  int gwid = (blockIdx.x * 256 + threadIdx.x) >> 6;
  int v, base;
  if (gwid < 1024)      { v = 0; base = 0; }
  else if (gwid < 3072) { v = 1; base = 1024; }
  else if (gwid < 7168) { v = 2; base = 3072; }
  else                  { v = 3; base = 7168; }
  int local = gwid - base;
  int b = local >> 8, d = local & 255;
  int Lp = 512 >> v;
  int t0 = b * Lp;
  const float* dtrow = DTT + ((long)(v * 256 + d)) * 2048 + t0;
  const float* dxrow = DXT + ((long)(v * 256 + d)) * 2048 + t0;
  const float* dblp = dbl + ((long)v * NT + t0) * 136;
  float* ysp = ys + (long)v * NT * Di + (long)((b << 8) + d) * Lp;
  float a2 = A2[d * 64 + lane];
  float h = 0.f;

#define LOADG(BB, CC, G)                                                     \
  _Pragma("unroll") for (int q = 0; q < 8; ++q) {                            \
    BB[q] = rowp[((G) * 8 + q) * 136 + 8 + lane];                            \
    CC[q] = rowp[((G) * 8 + q) * 136 + 72 + lane];                           \
  }
#define PROCG(BB, CC, G)                                                     \
  _Pragma("unroll") for (int q = 0; q < 8; ++q) {                            \
    int l2 = (G) * 8 + q;                                                    \
    float sdt = __int_as_float(__builtin_amdgcn_readlane(__float_as_int(rdt), l2)); \
    float sdx = __int_as_float(__builtin_amdgcn_readlane(__float_as_int(rdx), l2)); \
    float a = __builtin_amdgcn_exp2f(sdt * a2);                              \
    h = fmaf(a, h, sdx * BB[q]);                                             \
    float p = h * CC[q];                                                     \
    p = dpp_add<0x111>(p); p = dpp_add<0x112>(p);                            \
    p = dpp_add<0x114>(p); p = dpp_add<0x118>(p);                            \
    p = dpp_add<0x142>(p); p = dpp_add<0x143>(p);                            \
    float tot = __int_as_float(__builtin_amdgcn_readlane(__float_as_int(p), 63)); \
    if (lane == l2) ybuf = tot;                                              \
  }

  for (int c = 0; c < Lp; c += 64) {
    float rdt = dtrow[c + lane];
    float rdx = dxrow[c + lane];
    const float* rowp = dblp + (long)c * 136;
    float ybuf = 0.f;
    float b0[8], c0[8], b1[8], c1[8];
    LOADG(b0, c0, 0)
    LOADG(b1, c1, 1)
    PROCG(b0, c0, 0) LOADG(b0, c0, 2)
    PROCG(b1, c1, 1) LOADG(b1, c1, 3)
    PROCG(b0, c0, 2) LOADG(b0, c0, 4)
    PROCG(b1, c1, 3) LOADG(b1, c1, 5)
    PROCG(b0, c0, 4) LOADG(b0, c0, 6)
    PROCG(b1, c1, 5) LOADG(b1, c1, 7)
    PROCG(b0, c0, 6)
    PROCG(b1, c1, 7)
    ysp[c + lane] = ybuf;
  }
#undef LOADG
#undef PROCG
}

// ---------------------------------------------------------------------------
__global__ void k_yfull(const float* __restrict__ ys, const float* __restrict__ xh,
                        const float* __restrict__ xz, const float* __restrict__ Dp,
                        float* __restrict__ yacc) {
  int i = blockIdx.x * 256 + threadIdx.x;
  int t = i >> 8, d = i & 255;
  float z = xz[(long)t * 512 + 256 + d];
  float sil = z / (1.f + expf(-z));
  float Dd = Dp[d];
  float s = 0.f;
#pragma unroll
  for (int v = 0; v < 4; ++v) {
    int Lp = 512 >> v;
    int b = t >> (9 - v);
    int l = t & (Lp - 1);
    float ysv = ys[(long)v * NT * Di + (long)((b << 8) + d) * Lp + l];
    float xhv = xh[(long)v * NT * Di + i];
    s += ysv + Dd * xhv;
  }
  yacc[i] = s * sil;
}

// ---------------------------------------------------------------------------
__global__ __launch_bounds__(256) void k_bnstats(const float* __restrict__ h, int F,
                                                 const float* __restrict__ g,
                                                 const float* __restrict__ b,
                                                 float* __restrict__ scale,
                                                 float* __restrict__ shift) {
  int f = blockIdx.x;
  float s = 0.f, sq = 0.f;
  for (int t = threadIdx.x; t < NT; t += 256) {
    float v = h[(long)t * F + f];
    s += v; sq += v * v;
  }
#pragma unroll
  for (int off = 32; off; off >>= 1) { s += __shfl_xor(s, off); sq += __shfl_xor(sq, off); }
  __shared__ float red[2][4];
  int w = threadIdx.x >> 6;
  if ((threadIdx.x & 63) == 0) { red[0][w] = s; red[1][w] = sq; }
  __syncthreads();
  if (threadIdx.x == 0) {
    s = red[0][0] + red[0][1] + red[0][2] + red[0][3];
    sq = red[1][0] + red[1][1] + red[1][2] + red[1][3];
    float mu = s * (1.f / NT);
    float var = sq * (1.f / NT) - mu * mu;
    float sc = g[f] * rsqrtf(var + EPSF);
    scale[f] = sc;
    shift[f] = b[f] - mu * sc;
  }
}

// bnrelu + transpose-convert: H1NTb[b][f][t] = bf16(relu(h1*scale+shift))
__global__ __launch_bounds__(256) void k_bnreluT(const float* __restrict__ h1,
                                                 const float* __restrict__ scale,
                                                 const float* __restrict__ shift,
                                                 ushort* __restrict__ outT) {
  __shared__ float tile[64][65];
  int t0 = blockIdx.x * 64, f0 = blockIdx.y * 64, b = blockIdx.z;
  int tid = threadIdx.x;
#pragma unroll
  for (int i = 0; i < 16; ++i) {
    int idx = i * 256 + tid;
    int r = idx >> 6, c = idx & 63;
    int f = f0 + c;
    float v = h1[((long)(b * 512 + t0 + r)) * 256 + f];
    tile[r][c] = fmaxf(fmaf(v, scale[f], shift[f]), 0.f);
  }
  __syncthreads();
  int tc2 = (tid & 31) * 2, fr0 = tid >> 5;
#pragma unroll
  for (int i = 0; i < 8; ++i) {
    int fr = fr0 + i * 8;
    uint u = ((uint)bf16bits(tile[tc2 + 1][fr]) << 16) | bf16bits(tile[tc2][fr]);
    long off = (long)b * 131072 + (long)(f0 + fr) * 512 + t0 + tc2;
    *(uint*)(outT + off) = u;
  }
}

// freq op + transpose-convert: XRITb[b][f][ [xr(512);xi(512)] ]
__global__ __launch_bounds__(256) void k_freqT(const float* __restrict__ XRI,
                                               const float* __restrict__ rd,
                                               const float* __restrict__ idg,
                                               const float* __restrict__ rb,
                                               const float* __restrict__ ib,
                                               ushort* __restrict__ outT) {
  __shared__ float tr[64][65], ti[64][65];
  int n0 = blockIdx.x * 64, f0 = blockIdx.y * 64, b = blockIdx.z;
  int tid = threadIdx.x;
#pragma unroll
  for (int i = 0; i < 16; ++i) {
    int idx = i * 256 + tid;
    int r = idx >> 6, c = idx & 63;
    int f = f0 + c;
    long base = (long)b * 262144 + (long)(n0 + r) * 256 + f;
    float a = XRI[base], b2 = XRI[base + 131072];
    tr[r][c] = fmaxf(a * rd[f] - b2 * idg[f] + rb[f], 0.f);
    ti[r][c] = fmaxf(b2 * rd[f] + a * idg[f] + ib[f], 0.f);
  }
  __syncthreads();
  int tc2 = (tid & 31) * 2, fr0 = tid >> 5;
#pragma unroll
  for (int i = 0; i < 8; ++i) {
    int fr = fr0 + i * 8;
    long offr = (long)b * 262144 + (long)(f0 + fr) * 1024 + n0 + tc2;
    uint ur = ((uint)bf16bits(tr[tc2 + 1][fr]) << 16) | bf16bits(tr[tc2][fr]);
    uint ui = ((uint)bf16bits(ti[tc2 + 1][fr]) << 16) | bf16bits(ti[tc2][fr]);
    *(uint*)(outT + offr) = ur;
    *(uint*)(outT + offr + 512) = ui;
  }
}

__global__ void k_final(const float* __restrict__ xo, const float* __restrict__ f2,
                        const float* __restrict__ scale, const float* __restrict__ shift,
                        float* __restrict__ out) {
  int i = blockIdx.x * 256 + threadIdx.x;
  int c = i & 127;
  out[i] = xo[i] + fmaf(f2[i], scale[c], shift[c]);
}

// ---------------------------------------------------------------------------
extern "C" void kernel_launch(void* const* d_in, const int* in_sizes, int n_in,
                              void* d_out, int out_size, void* d_ws, size_t ws_size,
                              hipStream_t stream) {
  const float* x         = (const float*)d_in[0];
  const float* ln_w      = (const float*)d_in[1];
  const float* ln_b      = (const float*)d_in[2];
  const float* in_proj_w = (const float*)d_in[3];
  const float* conv_w    = (const float*)d_in[4];
  const float* conv_b    = (const float*)d_in[5];
  const float* x_proj_w  = (const float*)d_in[6];
  const float* dt_proj_w = (const float*)d_in[7];
  const float* dt_proj_b = (const float*)d_in[8];
  const float* A_log     = (const float*)d_in[9];
  const float* D_param   = (const float*)d_in[10];
  const float* out_proj_w= (const float*)d_in[11];
  const float* n1w       = (const float*)d_in[12];
  const float* n1b       = (const float*)d_in[13];
  const float* n2w       = (const float*)d_in[14];
  const float* n2b       = (const float*)d_in[15];
  const float* fc1_w     = (const float*)d_in[16];
  const float* bn1_g     = (const float*)d_in[17];
  const float* bn1_b     = (const float*)d_in[18];
  const float* r_mat     = (const float*)d_in[19];
  const float* i_mat     = (const float*)d_in[20];
  const float* rb        = (const float*)d_in[21];
  const float* ib        = (const float*)d_in[22];
  const float* fc2_w     = (const float*)d_in[23];
  const float* bn2_g     = (const float*)d_in[24];
  const float* bn2_b     = (const float*)d_in[25];
  float* ws  = (float*)d_ws;
  float* out = (float*)d_out;

  k_costab<<<1, 256, 0, stream>>>(ws);
  k_tables<<<4096, 256, 0, stream>>>(A_log, fc1_w, fc2_w, r_mat, i_mat, ws);
  k_ln1<<<512, 256, 0, stream>>>(x, ln_w, ln_b, ws + O_XN);
  k_gemm<<<dim3(8, 32, 1), 256, 0, stream>>>(ws + O_XN, in_proj_w, ws + O_XZ,
                                             NT, 512, 128, 0, 0, 0);
  k_conv<<<8192, 256, 0, stream>>>(ws + O_XZ, conv_w, conv_b, ws + O_XH);
  k_gemm<<<dim3(3, 32, 4), 256, 0, stream>>>(ws + O_XH, x_proj_w, ws + O_DBL,
                                             NT, 136, 256,
                                             (long)NT * Di, 0, (long)NT * 136);
  k_dtx<<<dim3(4, 32, 4), 256, 0, stream>>>(ws + O_DBL, ws + O_XH, dt_proj_w,
                                            dt_proj_b, ws + O_DTT, ws + O_DXT,
                                            out + 262144);
  k_scan<<<3840, 256, 0, stream>>>(ws + O_DTT, ws + O_DXT, ws + O_DBL,
                                   ws + O_A2, ws + O_YS);
  k_yfull<<<2048, 256, 0, stream>>>(ws + O_YS, ws + O_XH, ws + O_XZ, D_param,
                                    ws + O_YACC);
  k_gemm<<<dim3(2, 32, 1), 256, 0, stream>>>(ws + O_YACC, out_proj_w, ws + O_XO1,
                                             NT, 128, 256, 0, 0, 0);
  k_lndbl<<<512, 256, 0, stream>>>(x, ws + O_XO1, n1w, n1b, n2w, n2b,
                                   ws + O_XO, (__hip_bfloat16*)(ws + O_LN2B));
  // h1 = LN2b @ FC1b^T  (2048x256, K=128) -> fp32 H1
  k_gmfma<false><<<dim3(4, 32, 1), 256, 0, stream>>>(
      (const ushort*)(ws + O_LN2B), (const ushort*)(ws + O_FC1B), ws + O_H1,
      2048, 256, 128, 0, 0, 0);
  k_bnstats<<<256, 256, 0, stream>>>(ws + O_H1, 256, bn1_g, bn1_b,
                                     ws + O_ST1, ws + O_ST1 + 256);
  k_bnreluT<<<dim3(8, 4, 4), 256, 0, stream>>>(ws + O_H1, ws + O_ST1,
                                               ws + O_ST1 + 256,
                                               (ushort*)(ws + O_H1NTB));
  // fwd DFT: XRI_b = CS2b(1024x512) @ H1NTb_b^T -> fp32
  k_gmfma<false><<<dim3(4, 16, 4), 256, 0, stream>>>(
      (const ushort*)(ws + O_CS2B), (const ushort*)(ws + O_H1NTB), ws + O_XRI,
      1024, 256, 512, 0, 131072L, 262144L);
  k_freqT<<<dim3(8, 4, 4), 256, 0, stream>>>(ws + O_XRI, ws + O_RD, ws + O_IDG,
                                             rb, ib, (ushort*)(ws + O_XRITB));
  // inv DFT: H2b_b = CSIb(512x1024) @ XRITb_b^T -> bf16 (stride in bf16 elems)
  k_gmfma<true><<<dim3(4, 8, 4), 256, 0, stream>>>(
      (const ushort*)(ws + O_CSIB), (const ushort*)(ws + O_XRITB), ws + O_H2B,
      512, 256, 1024, 0, 262144L, 131072L);
  // f2 = H2b @ FC2b^T  (2048x128, K=256) -> fp32 F2
  k_gmfma<false><<<dim3(2, 32, 1), 256, 0, stream>>>(
      (const ushort*)(ws + O_H2B), (const ushort*)(ws + O_FC2B), ws + O_F2,
      2048, 128, 256, 0, 0, 0);
  k_bnstats<<<128, 256, 0, stream>>>(ws + O_F2, 128, bn2_g, bn2_b,
                                     ws + O_ST2, ws + O_ST2 + 128);
  k_final<<<1024, 256, 0, stream>>>(ws + O_XO, ws + O_F2, ws + O_ST2,
                                    ws + O_ST2 + 128, out);
}

// Round 5
// 297.546 us; speedup vs baseline: 2.0776x; 1.1091x over previous
//
#include <hip/hip_runtime.h>
#include <hip/hip_bf16.h>
#include <math.h>

// ---------------------------------------------------------------------------
// SABlock_CrossMamba. R5: all GEMMs bf16 MFMA (mamba path too); conv computes
// all 4 variants per thread (block-uniform fast path); costab merged into
// k_tables; tighter ws aliasing.
// ---------------------------------------------------------------------------

constexpr int NT = 2048;
constexpr int Di = 256;
constexpr float EPSF = 1e-5f;
constexpr float LOG2E = 1.4426950408889634f;
constexpr float ISQ512 = 0.04419417382415922f;  // 1/sqrt(512)

typedef __attribute__((ext_vector_type(8))) short short8;
typedef __attribute__((ext_vector_type(4))) float f32x4;

// ws layout (float offsets, 16B-aligned)
constexpr long O_CS2B  = 0;         // bf16 1024x512   -> 262144 fl
constexpr long O_CSIB  = 262144;    // bf16 512x1024   -> 262144 fl
constexpr long O_A2    = 524288;    // 16384 fl
constexpr long O_FC1B  = 540672;    // bf16 256x128    -> 16384 fl
constexpr long O_FC2B  = 557056;    // bf16 128x256    -> 16384 fl
constexpr long O_INPB  = 573440;    // bf16 512x128    -> 32768 fl
constexpr long O_XPB   = 606208;    // bf16 192x256    -> 24576 fl (pad 136->192)
constexpr long O_OPB   = 630784;    // bf16 128x256    -> 16384 fl
constexpr long O_RD    = 647168;    // 256
constexpr long O_IDG   = 647424;    // 256
constexpr long O_XNB   = 647680;    // bf16 2048x128   -> 131072 fl
constexpr long O_XZ    = 778752;    // 1048576 fl
constexpr long O_XH    = 1827328;   // 2097152 fl
constexpr long O_DBL   = 3924480;   // 1114112 fl
constexpr long O_DTT   = 5038592;   // 2097152 fl
constexpr long O_YS    = 7135744;   // 2097152 fl
constexpr long O_XO    = 9232896;   // 262144 fl
constexpr long O_LN2B  = 9495040;   // bf16 2048x128   -> 131072 fl
constexpr long O_H1    = 9626112;   // 524288 fl
constexpr long O_H1NTB = 10150400;  // bf16 4x256x512  -> 262144 fl
constexpr long O_XRI   = 10412544;  // 1048576 fl
constexpr long O_XRITB = 11461120;  // bf16 4x256x1024 -> 524288 fl
constexpr long O_H2B   = 11985408;  // bf16 2048x256   -> 262144 fl
constexpr long O_F2    = 12247552;  // 262144 fl
constexpr long O_ST1   = 12509696;  // 512
constexpr long O_ST2   = 12510208;  // 384
// Aliases (disjoint lifetimes):
constexpr long O_DXT   = O_H1;   // dtx->scan; region rewritten later by FFN
constexpr long O_XHB   = O_H1;   // conv->x_proj GEMM; dead before dtx writes DXT
constexpr long O_YACCB = O_F2;   // yfull->out_proj; F2 written much later
constexpr long O_XO1   = O_H2B;  // out_proj->lndbl; H2B written later

__device__ __forceinline__ ushort bf16bits(float v) {
  __hip_bfloat16 h = __float2bfloat16(v);
  return *(ushort*)&h;
}

// ---------------------------------------------------------------------------
// All tables: DFT matrices (via per-block LDS cos table), A2, bf16 weights.
__global__ __launch_bounds__(256) void k_tables(
    const float* __restrict__ A_log, const float* __restrict__ fc1_w,
    const float* __restrict__ fc2_w, const float* __restrict__ r_mat,
    const float* __restrict__ i_mat, const float* __restrict__ in_proj_w,
    const float* __restrict__ x_proj_w, const float* __restrict__ out_proj_w,
    float* __restrict__ ws) {
  __shared__ float ct[512];
  int tid = threadIdx.x;
  ct[tid]       = cosf((float)tid * (6.283185307179586f / 512.0f)) * ISQ512;
  ct[tid + 256] = cosf((float)(tid + 256) * (6.283185307179586f / 512.0f)) * ISQ512;
  __syncthreads();
  __hip_bfloat16* cs2b = (__hip_bfloat16*)(ws + O_CS2B);
  __hip_bfloat16* csib = (__hip_bfloat16*)(ws + O_CSIB);
  int i = blockIdx.x * 256 + tid;   // 1048576 threads
  if (i < 524288) {          // CS2[r][n]: r<512 cos(rn), else -sin((r-512)n)
    int r = i >> 9, n = i & 511;
    float v;
    if (r < 512) v = ct[(r * n) & 511];
    else         v = -ct[((r - 512) * n + 384) & 511];
    cs2b[i] = __float2bfloat16(v);
  } else {                   // CSI[n][kp]: kp<512 cos(n*kp), else -sin(n(kp-512))
    int j = i - 524288;
    int n = j >> 10, kp = j & 1023;
    float v;
    if (kp < 512) v = ct[(n * kp) & 511];
    else          v = -ct[(n * (kp - 512) + 384) & 511];
    csib[j] = __float2bfloat16(v);
  }
  if (i < 16384) ws[O_A2 + i] = -expf(A_log[i]) * LOG2E;
  if (i < 32768) {
    ((__hip_bfloat16*)(ws + O_FC1B))[i] = __float2bfloat16(fc1_w[i]);
    ((__hip_bfloat16*)(ws + O_FC2B))[i] = __float2bfloat16(fc2_w[i]);
  }
  if (i < 65536) {  // INPB[n][k] = in_proj_w[k][n]  (512x128)
    int n = i >> 7, k = i & 127;
    ((__hip_bfloat16*)(ws + O_INPB))[i] = __float2bfloat16(in_proj_w[k * 512 + n]);
  }
  if (i < 49152) {  // XPB[n][k] = x_proj_w[k][n], zero-padded n>=136 (192x256)
    int n = i >> 8, k = i & 255;
    float v = (n < 136) ? x_proj_w[k * 136 + n] : 0.f;
    ((__hip_bfloat16*)(ws + O_XPB))[i] = __float2bfloat16(v);
  }
  if (i < 32768 + 0) {}  // (spacing)
  if (i >= 65536 && i < 65536 + 32768) {  // OPB[n][k] = out_proj_w[k][n] (128x256)
    int j = i - 65536;
    int n = j >> 8, k = j & 255;
    ((__hip_bfloat16*)(ws + O_OPB))[j] = __float2bfloat16(out_proj_w[k * 128 + n]);
  }
  if (i < 256) {
    ws[O_RD + i] = r_mat[i * 256 + i];
    ws[O_IDG + i] = i_mat[i * 256 + i];
  }
}

// ---------------------------------------------------------------------------
// LayerNorm over D=128, one wave per token -> bf16
__global__ void k_ln1(const float* __restrict__ x, const float* __restrict__ w,
                      const float* __restrict__ b, ushort* __restrict__ outb) {
  int lane = threadIdx.x & 63;
  int t = (blockIdx.x * 256 + threadIdx.x) >> 6;
  float v0 = x[t * 128 + lane], v1 = x[t * 128 + 64 + lane];
  float s = v0 + v1, sq = v0 * v0 + v1 * v1;
#pragma unroll
  for (int off = 32; off; off >>= 1) { s += __shfl_xor(s, off); sq += __shfl_xor(sq, off); }
  float mu = s * (1.f / 128.f);
  float rstd = rsqrtf(sq * (1.f / 128.f) - mu * mu + EPSF);
  outb[t * 128 + lane]      = bf16bits((v0 - mu) * rstd * w[lane] + b[lane]);
  outb[t * 128 + 64 + lane] = bf16bits((v1 - mu) * rstd * w[64 + lane] + b[64 + lane]);
}

// xo = x + LN(x_o)*w1+b1 ; ln2b = bf16(LN(xo)*w2+b2)
__global__ void k_lndbl(const float* __restrict__ x, const float* __restrict__ xo1,
                        const float* __restrict__ w1, const float* __restrict__ b1,
                        const float* __restrict__ w2, const float* __restrict__ b2,
                        float* __restrict__ xo, ushort* __restrict__ ln2b) {
  int lane = threadIdx.x & 63;
  int t = (blockIdx.x * 256 + threadIdx.x) >> 6;
  float u0 = xo1[t * 128 + lane], u1 = xo1[t * 128 + 64 + lane];
  float s = u0 + u1, sq = u0 * u0 + u1 * u1;
#pragma unroll
  for (int off = 32; off; off >>= 1) { s += __shfl_xor(s, off); sq += __shfl_xor(sq, off); }
  float mu = s * (1.f / 128.f);
  float rstd = rsqrtf(sq * (1.f / 128.f) - mu * mu + EPSF);
  float a0 = x[t * 128 + lane]      + (u0 - mu) * rstd * w1[lane] + b1[lane];
  float a1 = x[t * 128 + 64 + lane] + (u1 - mu) * rstd * w1[64 + lane] + b1[64 + lane];
  xo[t * 128 + lane] = a0;
  xo[t * 128 + 64 + lane] = a1;
  s = a0 + a1; sq = a0 * a0 + a1 * a1;
#pragma unroll
  for (int off = 32; off; off >>= 1) { s += __shfl_xor(s, off); sq += __shfl_xor(sq, off); }
  mu = s * (1.f / 128.f);
  rstd = rsqrtf(sq * (1.f / 128.f) - mu * mu + EPSF);
  ln2b[t * 128 + lane]      = bf16bits((a0 - mu) * rstd * w2[lane] + b2[lane]);
  ln2b[t * 128 + 64 + lane] = bf16bits((a1 - mu) * rstd * w2[64 + lane] + b2[64 + lane]);
}

// ---------------------------------------------------------------------------
// bf16 MFMA GEMM: C = A @ Bt^T. A: MxK bf16 row-major; Bt: NtxK bf16 row-major
// (Nt >= N, rows >= n0+63 valid). M%64==0, K%32==0. Epilogue guards n < N.
template <bool OUTBF16>
__global__ __launch_bounds__(256) void k_gmfma(const ushort* __restrict__ A,
                                               const ushort* __restrict__ Bt,
                                               void* __restrict__ Cv,
                                               int M, int N, int K,
                                               long sA, long sBt, long sC) {
  A += (long)blockIdx.z * sA;
  Bt += (long)blockIdx.z * sBt;
  int lane = threadIdx.x & 63, wid = threadIdx.x >> 6;
  int m0 = blockIdx.y * 64 + wid * 16, n0 = blockIdx.x * 64;
  const ushort* arow = A + (long)(m0 + (lane & 15)) * K + (lane >> 4) * 8;
  const ushort* brow = Bt + (long)(n0 + (lane & 15)) * K + (lane >> 4) * 8;
  f32x4 acc0 = {0.f, 0.f, 0.f, 0.f}, acc1 = acc0, acc2 = acc0, acc3 = acc0;
#pragma unroll 4
  for (int k0 = 0; k0 < K; k0 += 32) {
    short8 av = *(const short8*)(arow + k0);
    short8 b0 = *(const short8*)(brow + k0);
    short8 b1 = *(const short8*)(brow + 16L * K + k0);
    short8 b2 = *(const short8*)(brow + 32L * K + k0);
    short8 b3 = *(const short8*)(brow + 48L * K + k0);
    acc0 = __builtin_amdgcn_mfma_f32_16x16x32_bf16(av, b0, acc0, 0, 0, 0);
    acc1 = __builtin_amdgcn_mfma_f32_16x16x32_bf16(av, b1, acc1, 0, 0, 0);
    acc2 = __builtin_amdgcn_mfma_f32_16x16x32_bf16(av, b2, acc2, 0, 0, 0);
    acc3 = __builtin_amdgcn_mfma_f32_16x16x32_bf16(av, b3, acc3, 0, 0, 0);
  }
  int r0 = (lane >> 4) * 4, c0 = lane & 15;
#pragma unroll
  for (int j = 0; j < 4; ++j) {
    long row = m0 + r0 + j;
    float v[4] = {acc0[j], acc1[j], acc2[j], acc3[j]};
    if (OUTBF16) {
      __hip_bfloat16* C = (__hip_bfloat16*)Cv + blockIdx.z * sC;
#pragma unroll
      for (int c = 0; c < 4; ++c) {
        int n = n0 + c * 16 + c0;
        if (n < N) C[row * N + n] = __float2bfloat16(v[c]);
      }
    } else {
      float* C = (float*)Cv + blockIdx.z * sC;
#pragma unroll
      for (int c = 0; c < 4; ++c) {
        int n = n0 + c * 16 + c0;
        if (n < N) C[row * N + n] = v[c];
      }
    }
  }
}

// ---------------------------------------------------------------------------
// Causal depthwise conv + SiLU, all 4 variants per thread.
// Block-uniform t -> fast path (identical variants) has no divergence.
__global__ void k_conv4(const float* __restrict__ xz, const float* __restrict__ cw,
                        const float* __restrict__ cb, float* __restrict__ xh,
                        ushort* __restrict__ xhb) {
  int i = blockIdx.x * 256 + threadIdx.x;  // NT*Di = 524288
  int t = i >> 8, d = i & 255;
  float w0 = cw[d * 4 + 0], w1 = cw[d * 4 + 1], w2 = cw[d * 4 + 2], w3 = cw[d * 4 + 3];
  float bias = cb[d];
  float x0  = xz[(long)t * 512 + d];
  float xm1 = t >= 1 ? xz[(long)(t - 1) * 512 + d] : 0.f;
  float xm2 = t >= 2 ? xz[(long)(t - 2) * 512 + d] : 0.f;
  float xm3 = t >= 3 ? xz[(long)(t - 3) * 512 + d] : 0.f;
  if ((t & 63) >= 3) {  // all variants identical (l0>=l1>=l2>=l3>=3)
    float s = fmaf(w0, xm3, fmaf(w1, xm2, fmaf(w2, xm1, fmaf(w3, x0, bias))));
    float sil = s / (1.f + expf(-s));
    ushort sb = bf16bits(sil);
#pragma unroll
    for (int v = 0; v < 4; ++v) { xh[v * 524288 + i] = sil; xhb[v * 524288 + i] = sb; }
  } else {
#pragma unroll
    for (int v = 0; v < 4; ++v) {
      int lv = t & ((512 >> v) - 1);
      float s = fmaf(w3, x0, bias);
      if (lv >= 1) s = fmaf(w2, xm1, s);
      if (lv >= 2) s = fmaf(w1, xm2, s);
      if (lv >= 3) s = fmaf(w0, xm3, s);
      float sil = s / (1.f + expf(-s));
      xh[v * 524288 + i] = sil;
      xhb[v * 524288 + i] = bf16bits(sil);
    }
  }
}

// ---------------------------------------------------------------------------
// dt/dx transposed producer + Cm output copy.
__global__ __launch_bounds__(256) void k_dtx(const float* __restrict__ dbl,
                                             const float* __restrict__ xh,
                                             const float* __restrict__ w,
                                             const float* __restrict__ bias,
                                             float* __restrict__ DTT,
                                             float* __restrict__ DXT,
                                             float* __restrict__ outC) {
  __shared__ float r8T[8][64];
  __shared__ float xt[64][65];
  __shared__ float wt[8][64];
  int v = blockIdx.z, t0 = blockIdx.y * 64, d0 = blockIdx.x * 64;
  int j = threadIdx.x;
  if (j < 128) {
    int t = j >> 1, half = j & 1;
    float4 q = *(const float4*)&dbl[((long)v * NT + t0 + t) * 136 + half * 4];
    r8T[half * 4 + 0][t] = q.x; r8T[half * 4 + 1][t] = q.y;
    r8T[half * 4 + 2][t] = q.z; r8T[half * 4 + 3][t] = q.w;
  } else {
    int idx = j - 128;
    int r = idx >> 4, dl4 = (idx & 15) * 4;
    float4 q = *(const float4*)&w[r * 256 + d0 + dl4];
    wt[r][dl4] = q.x; wt[r][dl4 + 1] = q.y; wt[r][dl4 + 2] = q.z; wt[r][dl4 + 3] = q.w;
  }
#pragma unroll
  for (int it = 0; it < 4; ++it) {
    int row = (j >> 4) + it * 16, col4 = (j & 15) * 4;
    float4 q = *(const float4*)&xh[((long)v * NT + t0 + row) * 256 + d0 + col4];
    xt[row][col4] = q.x; xt[row][col4 + 1] = q.y;
    xt[row][col4 + 2] = q.z; xt[row][col4 + 3] = q.w;
  }
  __syncthreads();
  int lane = j & 63, w4 = j >> 6;
#pragma unroll
  for (int k = 0; k < 16; ++k) {
    int dl = w4 * 16 + k, d = d0 + dl;
    float s = bias[d];
#pragma unroll
    for (int r = 0; r < 8; ++r) s = fmaf(r8T[r][lane], wt[r][dl], s);
    float dtv = fmaxf(s, 0.f) + log1pf(expf(-fabsf(s)));
    float dx = dtv * xt[lane][dl];
    long oi = ((long)(v * 256 + d)) * 2048 + t0 + lane;
    DTT[oi] = dtv;
    DXT[oi] = dx;
  }
  if (blockIdx.x == 0) {
#pragma unroll
    for (int k2 = 0; k2 < 16; ++k2) {
      int idx = k2 * 256 + j;
      int tl = idx >> 6, s2 = idx & 63;
      outC[(long)v * 131072 + (long)(t0 + tl) * 64 + s2] =
          dbl[((long)v * NT + t0 + tl) * 136 + 72 + s2];
    }
  }
}

// ---------------------------------------------------------------------------
template <int CTRL>
__device__ __forceinline__ float dpp_add(float x) {
  int t = __builtin_amdgcn_update_dpp(0, __float_as_int(x), CTRL, 0xF, 0xF, true);
  return x + __int_as_float(t);
}

// Selective scan, software-pipelined register prefetch (2 buf x 8 steps).
__global__ __launch_bounds__(256) void k_scan(const float* __restrict__ DTT,
                                              const float* __restrict__ DXT,
                                              const float* __restrict__ dbl,
                                              const float* __restrict__ A2,
                                              float* __restrict__ ys) {
  int lane = threadIdx.x & 63;
  int gwid = (blockIdx.x * 256 + threadIdx.x) >> 6;
  int v, base;
  if (gwid < 1024)      { v = 0; base = 0; }
  else if (gwid < 3072) { v = 1; base = 1024; }
  else if (gwid < 7168) { v = 2; base = 3072; }
  else                  { v = 3; base = 7168; }
  int local = gwid - base;
  int b = local >> 8, d = local & 255;
  int Lp = 512 >> v;
  int t0 = b * Lp;
  const float* dtrow = DTT + ((long)(v * 256 + d)) * 2048 + t0;
  const float* dxrow = DXT + ((long)(v * 256 + d)) * 2048 + t0;
  const float* dblp = dbl + ((long)v * NT + t0) * 136;
  float* ysp = ys + (long)v * NT * Di + (long)((b << 8) + d) * Lp;
  float a2 = A2[d * 64 + lane];
  float h = 0.f;

#define LOADG(BB, CC, G)                                                     \
  _Pragma("unroll") for (int q = 0; q < 8; ++q) {                            \
    BB[q] = rowp[((G) * 8 + q) * 136 + 8 + lane];                            \
    CC[q] = rowp[((G) * 8 + q) * 136 + 72 + lane];                           \
  }
#define PROCG(BB, CC, G)                                                     \
  _Pragma("unroll") for (int q = 0; q < 8; ++q) {                            \
    int l2 = (G) * 8 + q;                                                    \
    float sdt = __int_as_float(__builtin_amdgcn_readlane(__float_as_int(rdt), l2)); \
    float sdx = __int_as_float(__builtin_amdgcn_readlane(__float_as_int(rdx), l2)); \
    float a = __builtin_amdgcn_exp2f(sdt * a2);                              \
    h = fmaf(a, h, sdx * BB[q]);                                             \
    float p = h * CC[q];                                                     \
    p = dpp_add<0x111>(p); p = dpp_add<0x112>(p);                            \
    p = dpp_add<0x114>(p); p = dpp_add<0x118>(p);                            \
    p = dpp_add<0x142>(p); p = dpp_add<0x143>(p);                            \
    float tot = __int_as_float(__builtin_amdgcn_readlane(__float_as_int(p), 63)); \
    if (lane == l2) ybuf = tot;                                              \
  }

  for (int c = 0; c < Lp; c += 64) {
    float rdt = dtrow[c + lane];
    float rdx = dxrow[c + lane];
    const float* rowp = dblp + (long)c * 136;
    float ybuf = 0.f;
    float b0[8], c0[8], b1[8], c1[8];
    LOADG(b0, c0, 0)
    LOADG(b1, c1, 1)
    PROCG(b0, c0, 0) LOADG(b0, c0, 2)
    PROCG(b1, c1, 1) LOADG(b1, c1, 3)
    PROCG(b0, c0, 2) LOADG(b0, c0, 4)
    PROCG(b1, c1, 3) LOADG(b1, c1, 5)
    PROCG(b0, c0, 4) LOADG(b0, c0, 6)
    PROCG(b1, c1, 5) LOADG(b1, c1, 7)
    PROCG(b0, c0, 6)
    PROCG(b1, c1, 7)
    ysp[c + lane] = ybuf;
  }
#undef LOADG
#undef PROCG
}

// ---------------------------------------------------------------------------
// y = (ys + D*xh) summed over variants, * silu(z) -> bf16
__global__ void k_yfull(const float* __restrict__ ys, const float* __restrict__ xh,
                        const float* __restrict__ xz, const float* __restrict__ Dp,
                        ushort* __restrict__ yaccb) {
  int i = blockIdx.x * 256 + threadIdx.x;
  int t = i >> 8, d = i & 255;
  float z = xz[(long)t * 512 + 256 + d];
  float sil = z / (1.f + expf(-z));
  float Dd = Dp[d];
  float s = 0.f;
#pragma unroll
  for (int v = 0; v < 4; ++v) {
    int Lp = 512 >> v;
    int b = t >> (9 - v);
    int l = t & (Lp - 1);
    float ysv = ys[(long)v * NT * Di + (long)((b << 8) + d) * Lp + l];
    float xhv = xh[(long)v * NT * Di + i];
    s += ysv + Dd * xhv;
  }
  yaccb[i] = bf16bits(s * sil);
}

// ---------------------------------------------------------------------------
__global__ __launch_bounds__(256) void k_bnstats(const float* __restrict__ h, int F,
                                                 const float* __restrict__ g,
                                                 const float* __restrict__ b,
                                                 float* __restrict__ scale,
                                                 float* __restrict__ shift) {
  int f = blockIdx.x;
  float s = 0.f, sq = 0.f;
  for (int t = threadIdx.x; t < NT; t += 256) {
    float v = h[(long)t * F + f];
    s += v; sq += v * v;
  }
#pragma unroll
  for (int off = 32; off; off >>= 1) { s += __shfl_xor(s, off); sq += __shfl_xor(sq, off); }
  __shared__ float red[2][4];
  int w = threadIdx.x >> 6;
  if ((threadIdx.x & 63) == 0) { red[0][w] = s; red[1][w] = sq; }
  __syncthreads();
  if (threadIdx.x == 0) {
    s = red[0][0] + red[0][1] + red[0][2] + red[0][3];
    sq = red[1][0] + red[1][1] + red[1][2] + red[1][3];
    float mu = s * (1.f / NT);
    float var = sq * (1.f / NT) - mu * mu;
    float sc = g[f] * rsqrtf(var + EPSF);
    scale[f] = sc;
    shift[f] = b[f] - mu * sc;
  }
}

// bnrelu + transpose-convert: H1NTb[b][f][t] = bf16(relu(h1*scale+shift))
__global__ __launch_bounds__(256) void k_bnreluT(const float* __restrict__ h1,
                                                 const float* __restrict__ scale,
                                                 const float* __restrict__ shift,
                                                 ushort* __restrict__ outT) {
  __shared__ float tile[64][65];
  int t0 = blockIdx.x * 64, f0 = blockIdx.y * 64, b = blockIdx.z;
  int tid = threadIdx.x;
#pragma unroll
  for (int i = 0; i < 16; ++i) {
    int idx = i * 256 + tid;
    int r = idx >> 6, c = idx & 63;
    int f = f0 + c;
    float v = h1[((long)(b * 512 + t0 + r)) * 256 + f];
    tile[r][c] = fmaxf(fmaf(v, scale[f], shift[f]), 0.f);
  }
  __syncthreads();
  int tc2 = (tid & 31) * 2, fr0 = tid >> 5;
#pragma unroll
  for (int i = 0; i < 8; ++i) {
    int fr = fr0 + i * 8;
    uint u = ((uint)bf16bits(tile[tc2 + 1][fr]) << 16) | bf16bits(tile[tc2][fr]);
    long off = (long)b * 131072 + (long)(f0 + fr) * 512 + t0 + tc2;
    *(uint*)(outT + off) = u;
  }
}

// freq op + transpose-convert: XRITb[b][f][ xr(512);xi(512) ]
__global__ __launch_bounds__(256) void k_freqT(const float* __restrict__ XRI,
                                               const float* __restrict__ rd,
                                               const float* __restrict__ idg,
                                               const float* __restrict__ rb,
                                               const float* __restrict__ ib,
                                               ushort* __restrict__ outT) {
  __shared__ float tr[64][65], ti[64][65];
  int n0 = blockIdx.x * 64, f0 = blockIdx.y * 64, b = blockIdx.z;
  int tid = threadIdx.x;
#pragma unroll
  for (int i = 0; i < 16; ++i) {
    int idx = i * 256 + tid;
    int r = idx >> 6, c = idx & 63;
    int f = f0 + c;
    long base = (long)b * 262144 + (long)(n0 + r) * 256 + f;
    float a = XRI[base], b2 = XRI[base + 131072];
    tr[r][c] = fmaxf(a * rd[f] - b2 * idg[f] + rb[f], 0.f);
    ti[r][c] = fmaxf(b2 * rd[f] + a * idg[f] + ib[f], 0.f);
  }
  __syncthreads();
  int tc2 = (tid & 31) * 2, fr0 = tid >> 5;
#pragma unroll
  for (int i = 0; i < 8; ++i) {
    int fr = fr0 + i * 8;
    long offr = (long)b * 262144 + (long)(f0 + fr) * 1024 + n0 + tc2;
    uint ur = ((uint)bf16bits(tr[tc2 + 1][fr]) << 16) | bf16bits(tr[tc2][fr]);
    uint ui = ((uint)bf16bits(ti[tc2 + 1][fr]) << 16) | bf16bits(ti[tc2][fr]);
    *(uint*)(outT + offr) = ur;
    *(uint*)(outT + offr + 512) = ui;
  }
}

__global__ void k_final(const float* __restrict__ xo, const float* __restrict__ f2,
                        const float* __restrict__ scale, const float* __restrict__ shift,
                        float* __restrict__ out) {
  int i = blockIdx.x * 256 + threadIdx.x;
  int c = i & 127;
  out[i] = xo[i] + fmaf(f2[i], scale[c], shift[c]);
}

// ---------------------------------------------------------------------------
extern "C" void kernel_launch(void* const* d_in, const int* in_sizes, int n_in,
                              void* d_out, int out_size, void* d_ws, size_t ws_size,
                              hipStream_t stream) {
  const float* x         = (const float*)d_in[0];
  const float* ln_w      = (const float*)d_in[1];
  const float* ln_b      = (const float*)d_in[2];
  const float* in_proj_w = (const float*)d_in[3];
  const float* conv_w    = (const float*)d_in[4];
  const float* conv_b    = (const float*)d_in[5];
  const float* x_proj_w  = (const float*)d_in[6];
  const float* dt_proj_w = (const float*)d_in[7];
  const float* dt_proj_b = (const float*)d_in[8];
  const float* A_log     = (const float*)d_in[9];
  const float* D_param   = (const float*)d_in[10];
  const float* out_proj_w= (const float*)d_in[11];
  const float* n1w       = (const float*)d_in[12];
  const float* n1b       = (const float*)d_in[13];
  const float* n2w       = (const float*)d_in[14];
  const float* n2b       = (const float*)d_in[15];
  const float* fc1_w     = (const float*)d_in[16];
  const float* bn1_g     = (const float*)d_in[17];
  const float* bn1_b     = (const float*)d_in[18];
  const float* r_mat     = (const float*)d_in[19];
  const float* i_mat     = (const float*)d_in[20];
  const float* rb        = (const float*)d_in[21];
  const float* ib        = (const float*)d_in[22];
  const float* fc2_w     = (const float*)d_in[23];
  const float* bn2_g     = (const float*)d_in[24];
  const float* bn2_b     = (const float*)d_in[25];
  float* ws  = (float*)d_ws;
  float* out = (float*)d_out;

  k_tables<<<4096, 256, 0, stream>>>(A_log, fc1_w, fc2_w, r_mat, i_mat,
                                     in_proj_w, x_proj_w, out_proj_w, ws);
  k_ln1<<<512, 256, 0, stream>>>(x, ln_w, ln_b, (ushort*)(ws + O_XNB));
  // xz = xn @ in_proj_w : A=XNB(2048x128) Bt=INPB(512x128) -> fp32 XZ
  k_gmfma<false><<<dim3(8, 32, 1), 256, 0, stream>>>(
      (const ushort*)(ws + O_XNB), (const ushort*)(ws + O_INPB), ws + O_XZ,
      2048, 512, 128, 0, 0, 0);
  k_conv4<<<2048, 256, 0, stream>>>(ws + O_XZ, conv_w, conv_b, ws + O_XH,
                                    (ushort*)(ws + O_XHB));
  // dbl_v = xh_v @ x_proj_w : A=XHB_v(2048x256) Bt=XPB(192x256,padded) N=136
  k_gmfma<false><<<dim3(3, 32, 4), 256, 0, stream>>>(
      (const ushort*)(ws + O_XHB), (const ushort*)(ws + O_XPB), ws + O_DBL,
      2048, 136, 256, 524288L, 0, 278528L);
  k_dtx<<<dim3(4, 32, 4), 256, 0, stream>>>(ws + O_DBL, ws + O_XH, dt_proj_w,
                                            dt_proj_b, ws + O_DTT, ws + O_DXT,
                                            out + 262144);
  k_scan<<<3840, 256, 0, stream>>>(ws + O_DTT, ws + O_DXT, ws + O_DBL,
                                   ws + O_A2, ws + O_YS);
  k_yfull<<<2048, 256, 0, stream>>>(ws + O_YS, ws + O_XH, ws + O_XZ, D_param,
                                    (ushort*)(ws + O_YACCB));
  // x_o = yacc @ out_proj_w : A=YACCB(2048x256) Bt=OPB(128x256) -> fp32 XO1
  k_gmfma<false><<<dim3(2, 32, 1), 256, 0, stream>>>(
      (const ushort*)(ws + O_YACCB), (const ushort*)(ws + O_OPB), ws + O_XO1,
      2048, 128, 256, 0, 0, 0);
  k_lndbl<<<512, 256, 0, stream>>>(x, ws + O_XO1, n1w, n1b, n2w, n2b,
                                   ws + O_XO, (ushort*)(ws + O_LN2B));
  // h1 = LN2b @ FC1b^T -> fp32 H1
  k_gmfma<false><<<dim3(4, 32, 1), 256, 0, stream>>>(
      (const ushort*)(ws + O_LN2B), (const ushort*)(ws + O_FC1B), ws + O_H1,
      2048, 256, 128, 0, 0, 0);
  k_bnstats<<<256, 256, 0, stream>>>(ws + O_H1, 256, bn1_g, bn1_b,
                                     ws + O_ST1, ws + O_ST1 + 256);
  k_bnreluT<<<dim3(8, 4, 4), 256, 0, stream>>>(ws + O_H1, ws + O_ST1,
                                               ws + O_ST1 + 256,
                                               (ushort*)(ws + O_H1NTB));
  // fwd DFT: XRI_b = CS2b(1024x512) @ H1NTb_b^T -> fp32
  k_gmfma<false><<<dim3(4, 16, 4), 256, 0, stream>>>(
      (const ushort*)(ws + O_CS2B), (const ushort*)(ws + O_H1NTB), ws + O_XRI,
      1024, 256, 512, 0, 131072L, 262144L);
  k_freqT<<<dim3(8, 4, 4), 256, 0, stream>>>(ws + O_XRI, ws + O_RD, ws + O_IDG,
                                             rb, ib, (ushort*)(ws + O_XRITB));
  // inv DFT: H2b_b = CSIb(512x1024) @ XRITb_b^T -> bf16
  k_gmfma<true><<<dim3(4, 8, 4), 256, 0, stream>>>(
      (const ushort*)(ws + O_CSIB), (const ushort*)(ws + O_XRITB), ws + O_H2B,
      512, 256, 1024, 0, 262144L, 131072L);
  // f2 = H2b @ FC2b^T -> fp32 F2
  k_gmfma<false><<<dim3(2, 32, 1), 256, 0, stream>>>(
      (const ushort*)(ws + O_H2B), (const ushort*)(ws + O_FC2B), ws + O_F2,
      2048, 128, 256, 0, 0, 0);
  k_bnstats<<<128, 256, 0, stream>>>(ws + O_F2, 128, bn2_g, bn2_b,
                                     ws + O_ST2, ws + O_ST2 + 128);
  k_final<<<1024, 256, 0, stream>>>(ws + O_XO, ws + O_F2, ws + O_ST2,
                                    ws + O_ST2 + 128, out);
}

// Round 6
// 292.696 us; speedup vs baseline: 2.1120x; 1.0166x over previous
//
#include <hip/hip_runtime.h>
#include <hip/hip_bf16.h>
#include <math.h>

// ---------------------------------------------------------------------------
// SABlock_CrossMamba. R6: bf16-only xz/xh (no fp32 copies); coalesced BN
// partial sums via atomics + inline scale/shift in consumers; ln1 fused into
// k_tables.
// ---------------------------------------------------------------------------

constexpr int NT = 2048;
constexpr int Di = 256;
constexpr float EPSF = 1e-5f;
constexpr float LOG2E = 1.4426950408889634f;
constexpr float ISQ512 = 0.04419417382415922f;  // 1/sqrt(512)

typedef __attribute__((ext_vector_type(8))) short short8;
typedef __attribute__((ext_vector_type(4))) float f32x4;

// ws layout (float offsets, 16B-aligned)
constexpr long O_CS2B  = 0;         // bf16 1024x512   -> 262144 fl
constexpr long O_CSIB  = 262144;    // bf16 512x1024   -> 262144 fl
constexpr long O_A2    = 524288;    // 16384 fl
constexpr long O_FC1B  = 540672;    // bf16 256x128    -> 16384 fl
constexpr long O_FC2B  = 557056;    // bf16 128x256    -> 16384 fl
constexpr long O_INPB  = 573440;    // bf16 512x128    -> 32768 fl
constexpr long O_XPB   = 606208;    // bf16 192x256    -> 24576 fl (pad 136->192)
constexpr long O_OPB   = 630784;    // bf16 128x256    -> 16384 fl
constexpr long O_RD    = 647168;    // 256
constexpr long O_IDG   = 647424;    // 256
constexpr long O_XNB   = 647680;    // bf16 2048x128   -> 131072 fl
constexpr long O_XZB   = 778752;    // bf16 2048x512   -> 524288 fl
constexpr long O_XHB   = 1827328;   // bf16 4x2048x256 -> 1048576 fl
constexpr long O_DBL   = 3924480;   // 1114112 fl
constexpr long O_DTT   = 5038592;   // 2097152 fl
constexpr long O_YS    = 7135744;   // 2097152 fl
constexpr long O_XO    = 9232896;   // 262144 fl
constexpr long O_LN2B  = 9495040;   // bf16 2048x128   -> 131072 fl
constexpr long O_H1    = 9626112;   // 524288 fl
constexpr long O_H1NTB = 10150400;  // bf16 4x256x512  -> 262144 fl
constexpr long O_XRI   = 10412544;  // 1048576 fl
constexpr long O_XRITB = 11461120;  // bf16 4x256x1024 -> 524288 fl
constexpr long O_H2B   = 11985408;  // bf16 2048x256   -> 262144 fl
constexpr long O_F2    = 12247552;  // 262144 fl
constexpr long O_SQ1   = 12509696;  // 512  (S1[256], Q1[256])
constexpr long O_SQ2   = 12510208;  // 256  (S2[128], Q2[128])
// Aliases (disjoint lifetimes):
constexpr long O_DXT   = O_H1;    // dtx->scan; H1 written after yfull
constexpr long O_YACCB = O_F2;    // yfull->out_proj; F2 written much later
constexpr long O_XO1   = O_H2B;   // out_proj->lndbl; H2B written later

__device__ __forceinline__ ushort bf16bits(float v) {
  __hip_bfloat16 h = __float2bfloat16(v);
  return *(ushort*)&h;
}
__device__ __forceinline__ float bfu(ushort u) {
  return __uint_as_float((uint)u << 16);
}

// ---------------------------------------------------------------------------
// Tables + ln1 (blocks 0..511) + zero BN accumulators.
__global__ __launch_bounds__(256) void k_tables(
    const float* __restrict__ A_log, const float* __restrict__ fc1_w,
    const float* __restrict__ fc2_w, const float* __restrict__ r_mat,
    const float* __restrict__ i_mat, const float* __restrict__ in_proj_w,
    const float* __restrict__ x_proj_w, const float* __restrict__ out_proj_w,
    const float* __restrict__ x, const float* __restrict__ ln_w,
    const float* __restrict__ ln_b, float* __restrict__ ws) {
  __shared__ float ct[512];
  int tid = threadIdx.x;
  ct[tid]       = cosf((float)tid * (6.283185307179586f / 512.0f)) * ISQ512;
  ct[tid + 256] = cosf((float)(tid + 256) * (6.283185307179586f / 512.0f)) * ISQ512;
  __syncthreads();
  __hip_bfloat16* cs2b = (__hip_bfloat16*)(ws + O_CS2B);
  __hip_bfloat16* csib = (__hip_bfloat16*)(ws + O_CSIB);
  int i = blockIdx.x * 256 + tid;   // 1048576 threads
  if (i < 524288) {          // CS2[r][n]: r<512 cos(rn), else -sin((r-512)n)
    int r = i >> 9, n = i & 511;
    float v;
    if (r < 512) v = ct[(r * n) & 511];
    else         v = -ct[((r - 512) * n + 384) & 511];
    cs2b[i] = __float2bfloat16(v);
  } else {                   // CSI[n][kp]: kp<512 cos(n*kp), else -sin(n(kp-512))
    int j = i - 524288;
    int n = j >> 10, kp = j & 1023;
    float v;
    if (kp < 512) v = ct[(n * kp) & 511];
    else          v = -ct[(n * (kp - 512) + 384) & 511];
    csib[j] = __float2bfloat16(v);
  }
  if (i < 16384) ws[O_A2 + i] = -expf(A_log[i]) * LOG2E;
  if (i < 32768) {
    ((__hip_bfloat16*)(ws + O_FC1B))[i] = __float2bfloat16(fc1_w[i]);
    ((__hip_bfloat16*)(ws + O_FC2B))[i] = __float2bfloat16(fc2_w[i]);
  }
  if (i < 65536) {  // INPB[n][k] = in_proj_w[k][n]  (512x128)
    int n = i >> 7, k = i & 127;
    ((__hip_bfloat16*)(ws + O_INPB))[i] = __float2bfloat16(in_proj_w[k * 512 + n]);
  }
  if (i < 49152) {  // XPB[n][k] = x_proj_w[k][n], zero-padded n>=136 (192x256)
    int n = i >> 8, k = i & 255;
    float v = (n < 136) ? x_proj_w[k * 136 + n] : 0.f;
    ((__hip_bfloat16*)(ws + O_XPB))[i] = __float2bfloat16(v);
  }
  if (i >= 65536 && i < 98304) {  // OPB[n][k] = out_proj_w[k][n] (128x256)
    int j = i - 65536;
    int n = j >> 8, k = j & 255;
    ((__hip_bfloat16*)(ws + O_OPB))[j] = __float2bfloat16(out_proj_w[k * 128 + n]);
  }
  if (i < 256) {
    ws[O_RD + i] = r_mat[i * 256 + i];
    ws[O_IDG + i] = i_mat[i * 256 + i];
  }
  if (i < 512) ws[O_SQ1 + i] = 0.f;
  if (i < 256) ws[O_SQ2 + i] = 0.f;
  // ln1: blocks 0..511, one wave per token
  if (blockIdx.x < 512) {
    ushort* outb = (ushort*)(ws + O_XNB);
    int lane = tid & 63;
    int t = (blockIdx.x * 256 + tid) >> 6;
    float v0 = x[t * 128 + lane], v1 = x[t * 128 + 64 + lane];
    float s = v0 + v1, sq = v0 * v0 + v1 * v1;
#pragma unroll
    for (int off = 32; off; off >>= 1) { s += __shfl_xor(s, off); sq += __shfl_xor(sq, off); }
    float mu = s * (1.f / 128.f);
    float rstd = rsqrtf(sq * (1.f / 128.f) - mu * mu + EPSF);
    outb[t * 128 + lane]      = bf16bits((v0 - mu) * rstd * ln_w[lane] + ln_b[lane]);
    outb[t * 128 + 64 + lane] = bf16bits((v1 - mu) * rstd * ln_w[64 + lane] + ln_b[64 + lane]);
  }
}

// ---------------------------------------------------------------------------
// xo = x + LN(x_o)*w1+b1 ; ln2b = bf16(LN(xo)*w2+b2)
__global__ void k_lndbl(const float* __restrict__ x, const float* __restrict__ xo1,
                        const float* __restrict__ w1, const float* __restrict__ b1,
                        const float* __restrict__ w2, const float* __restrict__ b2,
                        float* __restrict__ xo, ushort* __restrict__ ln2b) {
  int lane = threadIdx.x & 63;
  int t = (blockIdx.x * 256 + threadIdx.x) >> 6;
  float u0 = xo1[t * 128 + lane], u1 = xo1[t * 128 + 64 + lane];
  float s = u0 + u1, sq = u0 * u0 + u1 * u1;
#pragma unroll
  for (int off = 32; off; off >>= 1) { s += __shfl_xor(s, off); sq += __shfl_xor(sq, off); }
  float mu = s * (1.f / 128.f);
  float rstd = rsqrtf(sq * (1.f / 128.f) - mu * mu + EPSF);
  float a0 = x[t * 128 + lane]      + (u0 - mu) * rstd * w1[lane] + b1[lane];
  float a1 = x[t * 128 + 64 + lane] + (u1 - mu) * rstd * w1[64 + lane] + b1[64 + lane];
  xo[t * 128 + lane] = a0;
  xo[t * 128 + 64 + lane] = a1;
  s = a0 + a1; sq = a0 * a0 + a1 * a1;
#pragma unroll
  for (int off = 32; off; off >>= 1) { s += __shfl_xor(s, off); sq += __shfl_xor(sq, off); }
  mu = s * (1.f / 128.f);
  rstd = rsqrtf(sq * (1.f / 128.f) - mu * mu + EPSF);
  ln2b[t * 128 + lane]      = bf16bits((a0 - mu) * rstd * w2[lane] + b2[lane]);
  ln2b[t * 128 + 64 + lane] = bf16bits((a1 - mu) * rstd * w2[64 + lane] + b2[64 + lane]);
}

// ---------------------------------------------------------------------------
// bf16 MFMA GEMM: C = A @ Bt^T. A: MxK bf16 row-major; Bt: NtxK bf16 row-major.
// M%64==0, K%32==0. Epilogue guards n < N.
template <bool OUTBF16>
__global__ __launch_bounds__(256) void k_gmfma(const ushort* __restrict__ A,
                                               const ushort* __restrict__ Bt,
                                               void* __restrict__ Cv,
                                               int M, int N, int K,
                                               long sA, long sBt, long sC) {
  A += (long)blockIdx.z * sA;
  Bt += (long)blockIdx.z * sBt;
  int lane = threadIdx.x & 63, wid = threadIdx.x >> 6;
  int m0 = blockIdx.y * 64 + wid * 16, n0 = blockIdx.x * 64;
  const ushort* arow = A + (long)(m0 + (lane & 15)) * K + (lane >> 4) * 8;
  const ushort* brow = Bt + (long)(n0 + (lane & 15)) * K + (lane >> 4) * 8;
  f32x4 acc0 = {0.f, 0.f, 0.f, 0.f}, acc1 = acc0, acc2 = acc0, acc3 = acc0;
#pragma unroll 4
  for (int k0 = 0; k0 < K; k0 += 32) {
    short8 av = *(const short8*)(arow + k0);
    short8 b0 = *(const short8*)(brow + k0);
    short8 b1 = *(const short8*)(brow + 16L * K + k0);
    short8 b2 = *(const short8*)(brow + 32L * K + k0);
    short8 b3 = *(const short8*)(brow + 48L * K + k0);
    acc0 = __builtin_amdgcn_mfma_f32_16x16x32_bf16(av, b0, acc0, 0, 0, 0);
    acc1 = __builtin_amdgcn_mfma_f32_16x16x32_bf16(av, b1, acc1, 0, 0, 0);
    acc2 = __builtin_amdgcn_mfma_f32_16x16x32_bf16(av, b2, acc2, 0, 0, 0);
    acc3 = __builtin_amdgcn_mfma_f32_16x16x32_bf16(av, b3, acc3, 0, 0, 0);
  }
  int r0 = (lane >> 4) * 4, c0 = lane & 15;
#pragma unroll
  for (int j = 0; j < 4; ++j) {
    long row = m0 + r0 + j;
    float v[4] = {acc0[j], acc1[j], acc2[j], acc3[j]};
    if (OUTBF16) {
      __hip_bfloat16* C = (__hip_bfloat16*)Cv + blockIdx.z * sC;
#pragma unroll
      for (int c = 0; c < 4; ++c) {
        int n = n0 + c * 16 + c0;
        if (n < N) C[row * N + n] = __float2bfloat16(v[c]);
      }
    } else {
      float* C = (float*)Cv + blockIdx.z * sC;
#pragma unroll
      for (int c = 0; c < 4; ++c) {
        int n = n0 + c * 16 + c0;
        if (n < N) C[row * N + n] = v[c];
      }
    }
  }
}

// ---------------------------------------------------------------------------
// Causal depthwise conv + SiLU, all 4 variants per thread (bf16 in/out).
__global__ void k_conv4(const ushort* __restrict__ xzb, const float* __restrict__ cw,
                        const float* __restrict__ cb, ushort* __restrict__ xhb) {
  int i = blockIdx.x * 256 + threadIdx.x;  // NT*Di = 524288
  int t = i >> 8, d = i & 255;
  float w0 = cw[d * 4 + 0], w1 = cw[d * 4 + 1], w2 = cw[d * 4 + 2], w3 = cw[d * 4 + 3];
  float bias = cb[d];
  float x0  = bfu(xzb[(long)t * 512 + d]);
  float xm1 = t >= 1 ? bfu(xzb[(long)(t - 1) * 512 + d]) : 0.f;
  float xm2 = t >= 2 ? bfu(xzb[(long)(t - 2) * 512 + d]) : 0.f;
  float xm3 = t >= 3 ? bfu(xzb[(long)(t - 3) * 512 + d]) : 0.f;
  if ((t & 63) >= 3) {  // all variants identical
    float s = fmaf(w0, xm3, fmaf(w1, xm2, fmaf(w2, xm1, fmaf(w3, x0, bias))));
    float sil = s / (1.f + expf(-s));
    ushort sb = bf16bits(sil);
#pragma unroll
    for (int v = 0; v < 4; ++v) xhb[v * 524288 + i] = sb;
  } else {
#pragma unroll
    for (int v = 0; v < 4; ++v) {
      int lv = t & ((512 >> v) - 1);
      float s = fmaf(w3, x0, bias);
      if (lv >= 1) s = fmaf(w2, xm1, s);
      if (lv >= 2) s = fmaf(w1, xm2, s);
      if (lv >= 3) s = fmaf(w0, xm3, s);
      float sil = s / (1.f + expf(-s));
      xhb[v * 524288 + i] = bf16bits(sil);
    }
  }
}

// ---------------------------------------------------------------------------
// dt/dx transposed producer + Cm output copy (xh now bf16).
__global__ __launch_bounds__(256) void k_dtx(const float* __restrict__ dbl,
                                             const ushort* __restrict__ xhb,
                                             const float* __restrict__ w,
                                             const float* __restrict__ bias,
                                             float* __restrict__ DTT,
                                             float* __restrict__ DXT,
                                             float* __restrict__ outC) {
  __shared__ float r8T[8][64];
  __shared__ float xt[64][65];
  __shared__ float wt[8][64];
  int v = blockIdx.z, t0 = blockIdx.y * 64, d0 = blockIdx.x * 64;
  int j = threadIdx.x;
  if (j < 128) {
    int t = j >> 1, half = j & 1;
    float4 q = *(const float4*)&dbl[((long)v * NT + t0 + t) * 136 + half * 4];
    r8T[half * 4 + 0][t] = q.x; r8T[half * 4 + 1][t] = q.y;
    r8T[half * 4 + 2][t] = q.z; r8T[half * 4 + 3][t] = q.w;
  } else {
    int idx = j - 128;
    int r = idx >> 4, dl4 = (idx & 15) * 4;
    float4 q = *(const float4*)&w[r * 256 + d0 + dl4];
    wt[r][dl4] = q.x; wt[r][dl4 + 1] = q.y; wt[r][dl4 + 2] = q.z; wt[r][dl4 + 3] = q.w;
  }
#pragma unroll
  for (int it = 0; it < 4; ++it) {
    int row = (j >> 4) + it * 16, col4 = (j & 15) * 4;
    uint2 u = *(const uint2*)&xhb[((long)v * NT + t0 + row) * 256 + d0 + col4];
    xt[row][col4 + 0] = __uint_as_float(u.x << 16);
    xt[row][col4 + 1] = __uint_as_float(u.x & 0xffff0000u);
    xt[row][col4 + 2] = __uint_as_float(u.y << 16);
    xt[row][col4 + 3] = __uint_as_float(u.y & 0xffff0000u);
  }
  __syncthreads();
  int lane = j & 63, w4 = j >> 6;
#pragma unroll
  for (int k = 0; k < 16; ++k) {
    int dl = w4 * 16 + k, d = d0 + dl;
    float s = bias[d];
#pragma unroll
    for (int r = 0; r < 8; ++r) s = fmaf(r8T[r][lane], wt[r][dl], s);
    float dtv = fmaxf(s, 0.f) + log1pf(expf(-fabsf(s)));
    float dx = dtv * xt[lane][dl];
    long oi = ((long)(v * 256 + d)) * 2048 + t0 + lane;
    DTT[oi] = dtv;
    DXT[oi] = dx;
  }
  if (blockIdx.x == 0) {
#pragma unroll
    for (int k2 = 0; k2 < 16; ++k2) {
      int idx = k2 * 256 + j;
      int tl = idx >> 6, s2 = idx & 63;
      outC[(long)v * 131072 + (long)(t0 + tl) * 64 + s2] =
          dbl[((long)v * NT + t0 + tl) * 136 + 72 + s2];
    }
  }
}

// ---------------------------------------------------------------------------
template <int CTRL>
__device__ __forceinline__ float dpp_add(float x) {
  int t = __builtin_amdgcn_update_dpp(0, __float_as_int(x), CTRL, 0xF, 0xF, true);
  return x + __int_as_float(t);
}

// Selective scan, software-pipelined register prefetch (2 buf x 8 steps).
__global__ __launch_bounds__(256) void k_scan(const float* __restrict__ DTT,
                                              const float* __restrict__ DXT,
                                              const float* __restrict__ dbl,
                                              const float* __restrict__ A2,
                                              float* __restrict__ ys) {
  int lane = threadIdx.x & 63;
  int gwid = (blockIdx.x * 256 + threadIdx.x) >> 6;
  int v, base;
  if (gwid < 1024)      { v = 0; base = 0; }
  else if (gwid < 3072) { v = 1; base = 1024; }
  else if (gwid < 7168) { v = 2; base = 3072; }
  else                  { v = 3; base = 7168; }
  int local = gwid - base;
  int b = local >> 8, d = local & 255;
  int Lp = 512 >> v;
  int t0 = b * Lp;
  const float* dtrow = DTT + ((long)(v * 256 + d)) * 2048 + t0;
  const float* dxrow = DXT + ((long)(v * 256 + d)) * 2048 + t0;
  const float* dblp = dbl + ((long)v * NT + t0) * 136;
  float* ysp = ys + (long)v * NT * Di + (long)((b << 8) + d) * Lp;
  float a2 = A2[d * 64 + lane];
  float h = 0.f;

#define LOADG(BB, CC, G)                                                     \
  _Pragma("unroll") for (int q = 0; q < 8; ++q) {                            \
    BB[q] = rowp[((G) * 8 + q) * 136 + 8 + lane];                            \
    CC[q] = rowp[((G) * 8 + q) * 136 + 72 + lane];                           \
  }
#define PROCG(BB, CC, G)                                                     \
  _Pragma("unroll") for (int q = 0; q < 8; ++q) {                            \
    int l2 = (G) * 8 + q;                                                    \
    float sdt = __int_as_float(__builtin_amdgcn_readlane(__float_as_int(rdt), l2)); \
    float sdx = __int_as_float(__builtin_amdgcn_readlane(__float_as_int(rdx), l2)); \
    float a = __builtin_amdgcn_exp2f(sdt * a2);                              \
    h = fmaf(a, h, sdx * BB[q]);                                             \
    float p = h * CC[q];                                                     \
    p = dpp_add<0x111>(p); p = dpp_add<0x112>(p);                            \
    p = dpp_add<0x114>(p); p = dpp_add<0x118>(p);                            \
    p = dpp_add<0x142>(p); p = dpp_add<0x143>(p);                            \
    float tot = __int_as_float(__builtin_amdgcn_readlane(__float_as_int(p), 63)); \
    if (lane == l2) ybuf = tot;                                              \
  }

  for (int c = 0; c < Lp; c += 64) {
    float rdt = dtrow[c + lane];
    float rdx = dxrow[c + lane];
    const float* rowp = dblp + (long)c * 136;
    float ybuf = 0.f;
    float b0[8], c0[8], b1[8], c1[8];
    LOADG(b0, c0, 0)
    LOADG(b1, c1, 1)
    PROCG(b0, c0, 0) LOADG(b0, c0, 2)
    PROCG(b1, c1, 1) LOADG(b1, c1, 3)
    PROCG(b0, c0, 2) LOADG(b0, c0, 4)
    PROCG(b1, c1, 3) LOADG(b1, c1, 5)
    PROCG(b0, c0, 4) LOADG(b0, c0, 6)
    PROCG(b1, c1, 5) LOADG(b1, c1, 7)
    PROCG(b0, c0, 6)
    PROCG(b1, c1, 7)
    ysp[c + lane] = ybuf;
  }
#undef LOADG
#undef PROCG
}

// ---------------------------------------------------------------------------
// y = (ys + D*xh) summed over variants, * silu(z) -> bf16
__global__ void k_yfull(const float* __restrict__ ys, const ushort* __restrict__ xhb,
                        const ushort* __restrict__ xzb, const float* __restrict__ Dp,
                        ushort* __restrict__ yaccb) {
  int i = blockIdx.x * 256 + threadIdx.x;
  int t = i >> 8, d = i & 255;
  float z = bfu(xzb[(long)t * 512 + 256 + d]);
  float sil = z / (1.f + expf(-z));
  float Dd = Dp[d];
  float s = 0.f;
#pragma unroll
  for (int v = 0; v < 4; ++v) {
    int Lp = 512 >> v;
    int b = t >> (9 - v);
    int l = t & (Lp - 1);
    float ysv = ys[(long)v * NT * Di + (long)((b << 8) + d) * Lp + l];
    float xhv = bfu(xhb[(long)v * 524288 + i]);
    s += ysv + Dd * xhv;
  }
  yaccb[i] = bf16bits(s * sil);
}

// ---------------------------------------------------------------------------
// Coalesced BN partial sums: 64 blocks, rows-major reads, atomic accumulate.
// SQ layout: [S[F], Q[F]] at SQ.
template <int F>
__global__ __launch_bounds__(256) void k_bnpart(const float* __restrict__ h,
                                                float* __restrict__ SQ) {
  constexpr int NREP = 256 / F;
  constexpr int TPR = 32 / NREP;          // tokens per rep
  int tid = threadIdx.x;
  int f = tid & (F - 1), rep = tid / F;
  int t0 = blockIdx.x * 32 + rep * TPR;
  float s = 0.f, q = 0.f;
#pragma unroll
  for (int tt = 0; tt < TPR; ++tt) {
    float v = h[(long)(t0 + tt) * F + f];
    s += v; q += v * v;
  }
  atomicAdd(&SQ[f], s);
  atomicAdd(&SQ[F + f], q);
}

// bnrelu + transpose-convert, scale/shift computed inline from SQ.
__global__ __launch_bounds__(256) void k_bnreluT(const float* __restrict__ h1,
                                                 const float* __restrict__ SQ,
                                                 const float* __restrict__ g,
                                                 const float* __restrict__ bb,
                                                 ushort* __restrict__ outT) {
  __shared__ float tile[64][65];
  __shared__ float sc_s[64], sh_s[64];
  int t0 = blockIdx.x * 64, f0 = blockIdx.y * 64, b = blockIdx.z;
  int tid = threadIdx.x;
  if (tid < 64) {
    int f = f0 + tid;
    float mu = SQ[f] * (1.f / NT);
    float var = SQ[256 + f] * (1.f / NT) - mu * mu;
    float sc = g[f] * rsqrtf(var + EPSF);
    sc_s[tid] = sc;
    sh_s[tid] = bb[f] - mu * sc;
  }
  __syncthreads();
#pragma unroll
  for (int i = 0; i < 16; ++i) {
    int idx = i * 256 + tid;
    int r = idx >> 6, c = idx & 63;
    float v = h1[((long)(b * 512 + t0 + r)) * 256 + f0 + c];
    tile[r][c] = fmaxf(fmaf(v, sc_s[c], sh_s[c]), 0.f);
  }
  __syncthreads();
  int tc2 = (tid & 31) * 2, fr0 = tid >> 5;
#pragma unroll
  for (int i = 0; i < 8; ++i) {
    int fr = fr0 + i * 8;
    uint u = ((uint)bf16bits(tile[tc2 + 1][fr]) << 16) | bf16bits(tile[tc2][fr]);
    long off = (long)b * 131072 + (long)(f0 + fr) * 512 + t0 + tc2;
    *(uint*)(outT + off) = u;
  }
}

// freq op + transpose-convert: XRITb[b][f][ xr(512);xi(512) ]
__global__ __launch_bounds__(256) void k_freqT(const float* __restrict__ XRI,
                                               const float* __restrict__ rd,
                                               const float* __restrict__ idg,
                                               const float* __restrict__ rb,
                                               const float* __restrict__ ib,
                                               ushort* __restrict__ outT) {
  __shared__ float tr[64][65], ti[64][65];
  int n0 = blockIdx.x * 64, f0 = blockIdx.y * 64, b = blockIdx.z;
  int tid = threadIdx.x;
#pragma unroll
  for (int i = 0; i < 16; ++i) {
    int idx = i * 256 + tid;
    int r = idx >> 6, c = idx & 63;
    int f = f0 + c;
    long base = (long)b * 262144 + (long)(n0 + r) * 256 + f;
    float a = XRI[base], b2 = XRI[base + 131072];
    tr[r][c] = fmaxf(a * rd[f] - b2 * idg[f] + rb[f], 0.f);
    ti[r][c] = fmaxf(b2 * rd[f] + a * idg[f] + ib[f], 0.f);
  }
  __syncthreads();
  int tc2 = (tid & 31) * 2, fr0 = tid >> 5;
#pragma unroll
  for (int i = 0; i < 8; ++i) {
    int fr = fr0 + i * 8;
    long offr = (long)b * 262144 + (long)(f0 + fr) * 1024 + n0 + tc2;
    uint ur = ((uint)bf16bits(tr[tc2 + 1][fr]) << 16) | bf16bits(tr[tc2][fr]);
    uint ui = ((uint)bf16bits(ti[tc2 + 1][fr]) << 16) | bf16bits(ti[tc2][fr]);
    *(uint*)(outT + offr) = ur;
    *(uint*)(outT + offr + 512) = ui;
  }
}

// final: out = xo + bn2(f2), scale/shift inline from SQ2.
__global__ __launch_bounds__(256) void k_final(const float* __restrict__ xo,
                                               const float* __restrict__ f2,
                                               const float* __restrict__ SQ,
                                               const float* __restrict__ g,
                                               const float* __restrict__ bb,
                                               float* __restrict__ out) {
  __shared__ float sc_s[128], sh_s[128];
  int tid = threadIdx.x;
  if (tid < 128) {
    float mu = SQ[tid] * (1.f / NT);
    float var = SQ[128 + tid] * (1.f / NT) - mu * mu;
    float sc = g[tid] * rsqrtf(var + EPSF);
    sc_s[tid] = sc;
    sh_s[tid] = bb[tid] - mu * sc;
  }
  __syncthreads();
  int i = blockIdx.x * 256 + tid;
  int c = i & 127;
  out[i] = xo[i] + fmaf(f2[i], sc_s[c], sh_s[c]);
}

// ---------------------------------------------------------------------------
extern "C" void kernel_launch(void* const* d_in, const int* in_sizes, int n_in,
                              void* d_out, int out_size, void* d_ws, size_t ws_size,
                              hipStream_t stream) {
  const float* x         = (const float*)d_in[0];
  const float* ln_w      = (const float*)d_in[1];
  const float* ln_b      = (const float*)d_in[2];
  const float* in_proj_w = (const float*)d_in[3];
  const float* conv_w    = (const float*)d_in[4];
  const float* conv_b    = (const float*)d_in[5];
  const float* x_proj_w  = (const float*)d_in[6];
  const float* dt_proj_w = (const float*)d_in[7];
  const float* dt_proj_b = (const float*)d_in[8];
  const float* A_log     = (const float*)d_in[9];
  const float* D_param   = (const float*)d_in[10];
  const float* out_proj_w= (const float*)d_in[11];
  const float* n1w       = (const float*)d_in[12];
  const float* n1b       = (const float*)d_in[13];
  const float* n2w       = (const float*)d_in[14];
  const float* n2b       = (const float*)d_in[15];
  const float* fc1_w     = (const float*)d_in[16];
  const float* bn1_g     = (const float*)d_in[17];
  const float* bn1_b     = (const float*)d_in[18];
  const float* r_mat     = (const float*)d_in[19];
  const float* i_mat     = (const float*)d_in[20];
  const float* rb        = (const float*)d_in[21];
  const float* ib        = (const float*)d_in[22];
  const float* fc2_w     = (const float*)d_in[23];
  const float* bn2_g     = (const float*)d_in[24];
  const float* bn2_b     = (const float*)d_in[25];
  float* ws  = (float*)d_ws;
  float* out = (float*)d_out;

  k_tables<<<4096, 256, 0, stream>>>(A_log, fc1_w, fc2_w, r_mat, i_mat,
                                     in_proj_w, x_proj_w, out_proj_w,
                                     x, ln_w, ln_b, ws);
  // xz = xn @ in_proj_w -> bf16 XZB
  k_gmfma<true><<<dim3(8, 32, 1), 256, 0, stream>>>(
      (const ushort*)(ws + O_XNB), (const ushort*)(ws + O_INPB), ws + O_XZB,
      2048, 512, 128, 0, 0, 0);
  k_conv4<<<2048, 256, 0, stream>>>((const ushort*)(ws + O_XZB), conv_w, conv_b,
                                    (ushort*)(ws + O_XHB));
  // dbl_v = xh_v @ x_proj_w -> fp32 DBL
  k_gmfma<false><<<dim3(3, 32, 4), 256, 0, stream>>>(
      (const ushort*)(ws + O_XHB), (const ushort*)(ws + O_XPB), ws + O_DBL,
      2048, 136, 256, 524288L, 0, 278528L);
  k_dtx<<<dim3(4, 32, 4), 256, 0, stream>>>(ws + O_DBL, (const ushort*)(ws + O_XHB),
                                            dt_proj_w, dt_proj_b, ws + O_DTT,
                                            ws + O_DXT, out + 262144);
  k_scan<<<3840, 256, 0, stream>>>(ws + O_DTT, ws + O_DXT, ws + O_DBL,
                                   ws + O_A2, ws + O_YS);
  k_yfull<<<2048, 256, 0, stream>>>(ws + O_YS, (const ushort*)(ws + O_XHB),
                                    (const ushort*)(ws + O_XZB), D_param,
                                    (ushort*)(ws + O_YACCB));
  // x_o = yacc @ out_proj_w -> fp32 XO1
  k_gmfma<false><<<dim3(2, 32, 1), 256, 0, stream>>>(
      (const ushort*)(ws + O_YACCB), (const ushort*)(ws + O_OPB), ws + O_XO1,
      2048, 128, 256, 0, 0, 0);
  k_lndbl<<<512, 256, 0, stream>>>(x, ws + O_XO1, n1w, n1b, n2w, n2b,
                                   ws + O_XO, (ushort*)(ws + O_LN2B));
  // h1 = LN2b @ FC1b^T -> fp32 H1
  k_gmfma<false><<<dim3(4, 32, 1), 256, 0, stream>>>(
      (const ushort*)(ws + O_LN2B), (const ushort*)(ws + O_FC1B), ws + O_H1,
      2048, 256, 128, 0, 0, 0);
  k_bnpart<256><<<64, 256, 0, stream>>>(ws + O_H1, ws + O_SQ1);
  k_bnreluT<<<dim3(8, 4, 4), 256, 0, stream>>>(ws + O_H1, ws + O_SQ1, bn1_g,
                                               bn1_b, (ushort*)(ws + O_H1NTB));
  // fwd DFT: XRI_b = CS2b @ H1NTb_b^T -> fp32
  k_gmfma<false><<<dim3(4, 16, 4), 256, 0, stream>>>(
      (const ushort*)(ws + O_CS2B), (const ushort*)(ws + O_H1NTB), ws + O_XRI,
      1024, 256, 512, 0, 131072L, 262144L);
  k_freqT<<<dim3(8, 4, 4), 256, 0, stream>>>(ws + O_XRI, ws + O_RD, ws + O_IDG,
                                             rb, ib, (ushort*)(ws + O_XRITB));
  // inv DFT: H2b_b = CSIb @ XRITb_b^T -> bf16
  k_gmfma<true><<<dim3(4, 8, 4), 256, 0, stream>>>(
      (const ushort*)(ws + O_CSIB), (const ushort*)(ws + O_XRITB), ws + O_H2B,
      512, 256, 1024, 0, 262144L, 131072L);
  // f2 = H2b @ FC2b^T -> fp32 F2
  k_gmfma<false><<<dim3(2, 32, 1), 256, 0, stream>>>(
      (const ushort*)(ws + O_H2B), (const ushort*)(ws + O_FC2B), ws + O_F2,
      2048, 128, 256, 0, 0, 0);
  k_bnpart<128><<<64, 256, 0, stream>>>(ws + O_F2, ws + O_SQ2);
  k_final<<<1024, 256, 0, stream>>>(ws + O_XO, ws + O_F2, ws + O_SQ2,
                                    bn2_g, bn2_b, out);
}